// Round 6
// baseline (229.772 us; speedup 1.0000x reference)
//
#include <hip/hip_runtime.h>
#include <cstdint>

#define DEVI __device__ __forceinline__

using fx4 = __attribute__((ext_vector_type(4))) float;
using bf8 = __attribute__((ext_vector_type(8))) __bf16;
using s8v = __attribute__((ext_vector_type(8))) short;
using s4v = __attribute__((ext_vector_type(4))) short;
typedef unsigned short u16;
typedef unsigned int u32;

DEVI float b2f(u16 u) { return __builtin_bit_cast(float, (u32)u << 16); }
DEVI u16 f2b(float f) {
  u32 u = __builtin_bit_cast(u32, f);
  return (u16)((u + 0x7fffu + ((u >> 16) & 1u)) >> 16);
}

// async global->LDS, 16B per lane, dest = wave-uniform base + lane*16
#define GLOAD(g, l)                                                          \
  __builtin_amdgcn_global_load_lds(                                          \
      (const __attribute__((address_space(1))) unsigned int*)(g),            \
      (__attribute__((address_space(3))) unsigned int*)(l), 16, 0, 0)

// ---- weight prep: W0->bf16; wqk8 [512][4096] (rows repeated 16x);
//      WvT; wcmul branch (Wc = Wsp@Wp, bc = Wsp@bp) ----
__global__ __launch_bounds__(256) void prep(const float* __restrict__ W0,
                                            const float* __restrict__ Wq,
                                            const float* __restrict__ Wk,
                                            const float* __restrict__ Wv,
                                            const float* __restrict__ Wsp,
                                            const float* __restrict__ Wp,
                                            const float* __restrict__ bp,
                                            u16* __restrict__ w0b,
                                            u16* __restrict__ wqk8,
                                            u16* __restrict__ wvtb,
                                            u16* __restrict__ wcb,
                                            float* __restrict__ bcb) {
  __shared__ float row[256];
  __shared__ float red[4];
  const int y = blockIdx.y;
  const int t = threadIdx.x;
  if (y == 0) {
    const int i = blockIdx.x * 256 + t;
    if (i < 131072) w0b[i] = f2b(W0[i]);
  } else if (y == 1) {
    // wqk8[row][k], k = s*512 + h*256 + yy : value = (row<256?Wq:Wk)[row&255][yy]
    const int i = blockIdx.x * 256 + t;        // 524288 quads total = exact
    const int r = i >> 10;                     // row 0..511
    const int q = (i & 1023) * 4;              // col base
    const int yy = q & 255;
    const float* src = (r < 256) ? (Wq + r * 256) : (Wk + (r - 256) * 256);
    s4v o;
#pragma unroll
    for (int j = 0; j < 4; ++j) o[j] = (short)f2b(src[yy + j]);
    *(s4v*)&wqk8[(long)r * 4096 + q] = o;
  } else if (y == 2) {
    const int i = blockIdx.x * 256 + t;
    if (i < 65536) {
      const int e = i >> 8, d = i & 255;
      wvtb[i] = f2b(Wv[d * 256 + e]);          // WvT[e,d] = Wv[d,e]
    }
  } else {
    if (blockIdx.x >= 256) return;
    const int o = blockIdx.x;
    row[t] = Wsp[o * 256 + t];
    __syncthreads();
    float acc = 0.f;
    for (int c = 0; c < 256; ++c) acc += row[c] * Wp[c * 256 + t];
    wcb[o * 256 + t] = f2b(acc);
    float pb = row[t] * bp[t];
#pragma unroll
    for (int m = 32; m > 0; m >>= 1) pb += __shfl_xor(pb, m);
    if ((t & 63) == 0) red[t >> 6] = pb;
    __syncthreads();
    if (t == 0) bcb[o] = red[0] + red[1] + red[2] + red[3];
  }
}

// ---- fused concat+1x1 conv: x0[b,n,o] = sum_c [fd;fs][b,c,n] * W0[o,c] ----
// 512 threads, tile 128(n) x 256(o), K=512(c). A staged from fp32 via
// two-stage LDS transpose; B via global_load_lds.
__global__ __launch_bounds__(512) void conv0f(const float* __restrict__ fd,
                                              const float* __restrict__ fs,
                                              const u16* __restrict__ w0b,
                                              u16* __restrict__ x0) {
  __shared__ u16 tmp[64 * 132];     // [c][n], pad 4
  __shared__ u16 ldsA[128 * 64];    // [n][c] chunk-swizzled
  __shared__ u16 ldsB[256 * 64];    // [o][c] linear (GLOAD)
  const int b = blockIdx.y;
  const int bm = blockIdx.x * 128;
  const int t = threadIdx.x;
  const int wid = t >> 6, lane = t & 63;
  const int wm = wid >> 2, wn = wid & 3;
  fx4 acc[4][4] = {};
  for (int kt = 0; kt < 512; kt += 64) {
    // B: 256 o-rows x 64 c  (4 GLOAD passes)
#pragma unroll
    for (int i = 0; i < 4; ++i) {
      const int r = i * 64 + (t >> 3);
      const int kq = (t & 7) ^ (r & 7);
      GLOAD(w0b + (long)r * 512 + kt + kq * 8, &ldsB[i * 4096 + wid * 512]);
    }
    // A stage1: 64c x 128n fp32 -> bf16 tmp[c][n]
    const float* src = ((kt < 256) ? fd : fs) + ((long)b * 256 + (kt & 255)) * 4096L + bm;
#pragma unroll
    for (int p = 0; p < 4; ++p) {
      const int c = (t >> 5) + p * 16;
      const int n4 = (t & 31) * 4;
      const fx4 v = *(const fx4*)&src[(long)c * 4096 + n4];
      s4v pk;
#pragma unroll
      for (int j = 0; j < 4; ++j) pk[j] = (short)f2b(v[j]);
      *(s4v*)&tmp[c * 132 + n4] = pk;
    }
    __syncthreads();
    // A stage2: tmp -> ldsA[n][c] swizzled
#pragma unroll
    for (int pass = 0; pass < 2; ++pass) {
      const int n = t & 127;
      const int g = (t >> 7) + pass * 4;
      s8v pk;
#pragma unroll
      for (int j = 0; j < 8; ++j) pk[j] = (short)tmp[(g * 8 + j) * 132 + n];
      *(s8v*)&ldsA[n * 64 + ((g ^ (n & 7)) * 8)] = pk;
    }
    __syncthreads();
#pragma unroll
    for (int ko = 0; ko < 2; ++ko) {
      bf8 af[4], bfr[4];
      const int kq = ko * 4 + (lane >> 4);
#pragma unroll
      for (int f = 0; f < 4; ++f) {
        const int ar = wm * 64 + f * 16 + (lane & 15);
        af[f] = *(const bf8*)&ldsA[ar * 64 + ((kq ^ (ar & 7)) * 8)];
        const int br = wn * 64 + f * 16 + (lane & 15);
        bfr[f] = *(const bf8*)&ldsB[br * 64 + ((kq ^ (br & 7)) * 8)];
      }
#pragma unroll
      for (int fm = 0; fm < 4; ++fm)
#pragma unroll
        for (int fn = 0; fn < 4; ++fn)
          acc[fm][fn] = __builtin_amdgcn_mfma_f32_16x16x32_bf16(af[fm], bfr[fn], acc[fm][fn], 0, 0, 0);
    }
    __syncthreads();
  }
#pragma unroll
  for (int fm = 0; fm < 4; ++fm) {
    const int m0 = wm * 64 + fm * 16 + ((lane >> 4) << 2);
#pragma unroll
    for (int fn = 0; fn < 4; ++fn) {
      const int o = wn * 64 + fn * 16 + (lane & 15);
#pragma unroll
      for (int r = 0; r < 4; ++r)
        x0[((long)b << 20) + (long)(bm + m0 + r) * 256 + o] = f2b(acc[fm][fn][r]);
    }
  }
}

// ---- bf16 NT GEMM: C[m,n] = sum_k A[m,k]*B[n,k] ----
// BIAS: 0 none, 2 bias[m]. POOL: per-tile row sums.
// EPI: 0 normal; 1 = S2 hi/lo (rows<256) + diag partials; 3 = part2 hi/lo.
template <typename OT, int BIAS, bool POOL, int EPI>
__global__ __launch_bounds__(256) void gemm_nt(
    const u16* __restrict__ A, long sA, int lda,
    const u16* __restrict__ B, long sB, int ldb,
    OT* __restrict__ C, long sC, long sCs, int ldc,
    const float* __restrict__ bias, int Keff, int ksplit,
    float* __restrict__ poolpart,
    const float* __restrict__ wqf, const float* __restrict__ wkf,
    float* __restrict__ dpart) {
  __shared__ u16 ldsA[128 * 64];
  __shared__ u16 ldsB[128 * 64];
  const int z = blockIdx.z;
  const int bb = z / ksplit;
  const int ss = z - bb * ksplit;
  const int bm = blockIdx.x * 128;
  const int bn = blockIdx.y * 128;
  const u16* Ab = A + bb * sA + (long)ss * Keff + (long)bm * lda;
  const u16* Bb = B + bb * sB + (long)ss * Keff + (long)bn * ldb;
  const int tid = threadIdx.x;
  const int wid = tid >> 6;
  const int lane = tid & 63;
  const int wm = wid >> 1, wn = wid & 1;
  const int srow = tid >> 3;
  const int slot = tid & 7;

  fx4 acc[4][4] = {};
  for (int kt = 0; kt < Keff; kt += 64) {
#pragma unroll
    for (int i = 0; i < 4; ++i) {
      const int row = i * 32 + srow;
      const int kq = slot ^ (row & 7);
      GLOAD(Ab + (long)row * lda + kt + kq * 8, &ldsA[i * 2048 + wid * 512]);
      GLOAD(Bb + (long)row * ldb + kt + kq * 8, &ldsB[i * 2048 + wid * 512]);
    }
    __syncthreads();
#pragma unroll
    for (int ko = 0; ko < 2; ++ko) {
      bf8 af[4], bfr[4];
      const int kq = ko * 4 + (lane >> 4);
#pragma unroll
      for (int f = 0; f < 4; ++f) {
        const int ar = wm * 64 + f * 16 + (lane & 15);
        af[f] = *(const bf8*)&ldsA[ar * 64 + ((kq ^ (ar & 7)) * 8)];
        const int br = wn * 64 + f * 16 + (lane & 15);
        bfr[f] = *(const bf8*)&ldsB[br * 64 + ((kq ^ (br & 7)) * 8)];
      }
#pragma unroll
      for (int fm = 0; fm < 4; ++fm)
#pragma unroll
        for (int fn = 0; fn < 4; ++fn)
          acc[fm][fn] = __builtin_amdgcn_mfma_f32_16x16x32_bf16(af[fm], bfr[fn], acc[fm][fn], 0, 0, 0);
    }
    __syncthreads();
  }
  if constexpr (EPI == 3) {
    // part2[b][m][ss*512 + (hi:n | lo:256+n)] = hi/lo of G_ss[m,n]
    u16* Pb = (u16*)C + bb * sC;
#pragma unroll
    for (int fm = 0; fm < 4; ++fm) {
      const int m0 = bm + wm * 64 + fm * 16 + ((lane >> 4) << 2);
#pragma unroll
      for (int fn = 0; fn < 4; ++fn) {
        const int n0 = bn + wn * 64 + fn * 16 + (lane & 15);
#pragma unroll
        for (int r = 0; r < 4; ++r) {
          const float v = acc[fm][fn][r];
          const u16 hi = f2b(v);
          const long base = (long)(m0 + r) * 4096 + ss * 512 + n0;
          Pb[base] = hi;
          Pb[base + 256] = f2b(v - b2f(hi));
        }
      }
    }
    return;
  }
  if constexpr (EPI == 1) {
    // S2 hi/lo write for rows<256 + diag partials for all rows
    u16* S2b = (u16*)C + bb * sC;
    float dp[4][4];
#pragma unroll
    for (int fm = 0; fm < 4; ++fm)
#pragma unroll
      for (int r = 0; r < 4; ++r) dp[fm][r] = 0.f;
#pragma unroll
    for (int fm = 0; fm < 4; ++fm) {
      const int m0 = bm + wm * 64 + fm * 16 + ((lane >> 4) << 2);
#pragma unroll
      for (int fn = 0; fn < 4; ++fn) {
        const int n0 = bn + wn * 64 + fn * 16 + (lane & 15);
#pragma unroll
        for (int r = 0; r < 4; ++r) {
          const float v = acc[fm][fn][r];
          const int m = m0 + r;
          if (m < 256) {
            const u16 hi = f2b(v);
            S2b[(long)m * 512 + n0] = hi;
            S2b[(long)m * 512 + 256 + n0] = f2b(v - b2f(hi));
          }
          const float* wr = (m < 256) ? (wqf + (long)m * 256) : (wkf + (long)(m - 256) * 256);
          dp[fm][r] += v * wr[n0];
        }
      }
    }
#pragma unroll
    for (int fm = 0; fm < 4; ++fm)
#pragma unroll
      for (int r = 0; r < 4; ++r) {
        float s = dp[fm][r];
        s += __shfl_xor(s, 1); s += __shfl_xor(s, 2);
        s += __shfl_xor(s, 4); s += __shfl_xor(s, 8);
        if ((lane & 15) == 0) {
          const int m = bm + wm * 64 + fm * 16 + ((lane >> 4) << 2) + r;
          dpart[(long)(blockIdx.y * 2 + wn) * 4096 + bb * 512 + m] = s;
        }
      }
    return;
  }
  OT* Cb = C + bb * sC + ss * sCs;
  float pr[4][4];
  if (POOL) {
#pragma unroll
    for (int fm = 0; fm < 4; ++fm)
#pragma unroll
      for (int r = 0; r < 4; ++r) pr[fm][r] = 0.f;
  }
#pragma unroll
  for (int fm = 0; fm < 4; ++fm) {
    const int m0 = bm + wm * 64 + fm * 16 + ((lane >> 4) << 2);
#pragma unroll
    for (int fn = 0; fn < 4; ++fn) {
      const int n0 = bn + wn * 64 + fn * 16 + (lane & 15);
#pragma unroll
      for (int r = 0; r < 4; ++r) {
        float v = acc[fm][fn][r];
        if (BIAS == 2) v += bias[m0 + r];
        if constexpr (sizeof(OT) == 2) Cb[(long)(m0 + r) * ldc + n0] = (OT)f2b(v);
        else Cb[(long)(m0 + r) * ldc + n0] = v;
        if (POOL) pr[fm][r] += v;
      }
    }
  }
  if (POOL) {
#pragma unroll
    for (int fm = 0; fm < 4; ++fm)
#pragma unroll
      for (int r = 0; r < 4; ++r) {
        float s = pr[fm][r];
        s += __shfl_xor(s, 1); s += __shfl_xor(s, 2);
        s += __shfl_xor(s, 4); s += __shfl_xor(s, 8);
        if ((lane & 15) == 0) {
          const int o = bm + wm * 64 + fm * 16 + ((lane >> 4) << 2) + r;
          poolpart[(long)(blockIdx.y * 2 + wn) * 2048 + bb * 256 + o] = s;
        }
      }
  }
}

// ---- depthwise 3x3 SAME, [B,N,C] bf16 layout ----
__global__ __launch_bounds__(256) void dwconv3x3(const u16* __restrict__ x,
                                                 const float* __restrict__ wdw,
                                                 u16* __restrict__ y) {
  __shared__ float w[9][256];
  const int t = threadIdx.x;
  for (int i = t; i < 2304; i += 256) w[i % 9][i / 9] = wdw[i];
  __syncthreads();
  const int nb = blockIdx.x;
  const int b = nb >> 9;
  const int n0 = (nb & 511) << 3;
  const int tn = t >> 5;
  const int tc = (t & 31) << 3;
  const int n = n0 + tn;
  const int hh = n >> 6, ww2 = n & 63;
  const u16* base = x + ((long)b << 20);
  float acc[8] = {0.f, 0.f, 0.f, 0.f, 0.f, 0.f, 0.f, 0.f};
#pragma unroll
  for (int ky = 0; ky < 3; ++ky) {
    const int hy = hh + ky - 1;
    if ((unsigned)hy >= 64u) continue;
#pragma unroll
    for (int kx = 0; kx < 3; ++kx) {
      const int wx = ww2 + kx - 1;
      if ((unsigned)wx >= 64u) continue;
      const s8v v = *(const s8v*)&base[(((hy << 6) + wx) << 8) + tc];
      const int kk = ky * 3 + kx;
      const fx4 wa = *(const fx4*)&w[kk][tc];
      const fx4 wb = *(const fx4*)&w[kk][tc + 4];
#pragma unroll
      for (int j = 0; j < 4; ++j) {
        acc[j] += wa[j] * b2f((u16)v[j]);
        acc[4 + j] += wb[j] * b2f((u16)v[4 + j]);
      }
    }
  }
  s8v o;
#pragma unroll
  for (int j = 0; j < 8; ++j) o[j] = (short)f2b(acc[j]);
  *(s8v*)&y[((long)b << 20) + ((long)n << 8) + tc] = o;
}

// ---- bf16 transpose: xt [B,4096,256] -> xtT [B,256,4096] ----
__global__ void btrans(const u16* __restrict__ x, u16* __restrict__ y) {
  __shared__ u16 t[32][34];
  const int b = blockIdx.z;
  const int n0 = blockIdx.x * 32;
  const int c0 = blockIdx.y * 32;
  const int tx = threadIdx.x, ty = threadIdx.y;
  const u16* sp = x + (long)b * 1048576 + (long)n0 * 256 + c0;
#pragma unroll
  for (int j = 0; j < 4; ++j) {
    int i = ty + j * 8;
    t[i][tx] = sp[(long)i * 256 + tx];
  }
  __syncthreads();
  u16* op = y + (long)b * 1048576 + (long)c0 * 4096 + n0;
#pragma unroll
  for (int j = 0; j < 4; ++j) {
    int r = ty + j * 8;
    op[(long)r * 4096 + tx] = t[tx][r];
  }
}

// ---- finalize rinv from diag partials + row softmax over d -> bf16 attn ----
__global__ __launch_bounds__(256) void softmax_g2(const float* __restrict__ araw,
                                                  const float* __restrict__ dpart,
                                                  u16* __restrict__ out) {
  const int wid = threadIdx.x >> 6, lane = threadIdx.x & 63;
  const int t = threadIdx.x;
  const int b = blockIdx.x >> 6;
  __shared__ float rq[256];
  float dq = dpart[b * 512 + t] + dpart[4096 + b * 512 + t] +
             dpart[8192 + b * 512 + t] + dpart[12288 + b * 512 + t];
  rq[t] = 1.f / fmaxf(sqrtf(fmaxf(dq, 0.f)), 1e-12f);
  __syncthreads();
  const long row = (long)blockIdx.x * 4 + wid;   // b*256 + c
  const int c = (int)(row & 255);
  const int ki = b * 512 + 256 + c;
  float dk = dpart[ki] + dpart[4096 + ki] + dpart[8192 + ki] + dpart[12288 + ki];
  const float rk = 1.f / fmaxf(sqrtf(fmaxf(dk, 0.f)), 1e-12f);
  fx4 v = ((const fx4*)(araw + row * 256))[lane];
  v[0] *= rk * rq[lane * 4];     v[1] *= rk * rq[lane * 4 + 1];
  v[2] *= rk * rq[lane * 4 + 2]; v[3] *= rk * rq[lane * 4 + 3];
  float m = fmaxf(fmaxf(v[0], v[1]), fmaxf(v[2], v[3]));
#pragma unroll
  for (int o = 32; o > 0; o >>= 1) m = fmaxf(m, __shfl_xor(m, o));
  float e0 = __expf(v[0] - m), e1 = __expf(v[1] - m);
  float e2 = __expf(v[2] - m), e3 = __expf(v[3] - m);
  float s4 = e0 + e1 + e2 + e3;
#pragma unroll
  for (int o = 32; o > 0; o >>= 1) s4 += __shfl_xor(s4, o);
  const float inv = 1.f / s4;
  u16* op = out + row * 256 + lane * 4;
  op[0] = f2b(e0 * inv); op[1] = f2b(e1 * inv);
  op[2] = f2b(e2 * inv); op[3] = f2b(e3 * inv);
}

// ---- SE gates: sum pooled partials + 2-layer MLP ----
__global__ __launch_bounds__(256) void se_gates(const float* __restrict__ poolpart,
                                                const float* __restrict__ w1d, const float* __restrict__ w2d,
                                                const float* __restrict__ w1s, const float* __restrict__ w2s,
                                                float* __restrict__ gd, float* __restrict__ gs) {
  const int b = blockIdx.x;
  const int t = threadIdx.x;
  __shared__ float p[256], hd[16], hs[16];
  float s = 0.f;
#pragma unroll 8
  for (int sl = 0; sl < 64; ++sl) s += poolpart[(long)sl * 2048 + b * 256 + t];
  p[t] = s * (1.f / 4096.f);
  __syncthreads();
  if (t < 16) {
    float ad = 0.f, as2 = 0.f;
    for (int j = 0; j < 256; ++j) {
      ad += w1d[t * 256 + j] * p[j];
      as2 += w1s[t * 256 + j] * p[j];
    }
    hd[t] = fmaxf(ad, 0.f);
    hs[t] = fmaxf(as2, 0.f);
  }
  __syncthreads();
  float ad = 0.f, as2 = 0.f;
#pragma unroll
  for (int r = 0; r < 16; ++r) {
    ad += w2d[t * 16 + r] * hd[r];
    as2 += w2s[t * 16 + r] * hs[r];
  }
  gd[b * 256 + t] = 1.f / (1.f + __expf(-ad));
  gs[b * 256 + t] = 1.f / (1.f + __expf(-as2));
}

// ---- final: out = outc(bf16)*gate + fp32 residual (layout-aligned) ----
__global__ __launch_bounds__(256) void fuse_out(const u16* __restrict__ oc,
                                                const float* __restrict__ gd, const float* __restrict__ gs,
                                                const float* __restrict__ fd, const float* __restrict__ fs,
                                                float* __restrict__ od, float* __restrict__ os) {
  const long i = ((long)blockIdx.x * 256 + threadIdx.x) * 8;
  const long bc = i >> 12;
  const float gdv = gd[bc], gsv = gs[bc];
  const s8v c8 = *(const s8v*)&oc[i];
  const fx4 a0 = *(const fx4*)(fd + i), a1 = *(const fx4*)(fd + i + 4);
  const fx4 s0 = *(const fx4*)(fs + i), s1 = *(const fx4*)(fs + i + 4);
  fx4 d0, d1, e0, e1;
#pragma unroll
  for (int j = 0; j < 4; ++j) {
    const float cl = b2f((u16)c8[j]);
    const float ch = b2f((u16)c8[4 + j]);
    d0[j] = cl * gdv + a0[j]; d1[j] = ch * gdv + a1[j];
    e0[j] = cl * gsv + s0[j]; e1[j] = ch * gsv + s1[j];
  }
  *(fx4*)(od + i) = d0; *(fx4*)(od + i + 4) = d1;
  *(fx4*)(os + i) = e0; *(fx4*)(os + i + 4) = e1;
}

extern "C" void kernel_launch(void* const* d_in, const int* in_sizes, int n_in,
                              void* d_out, int out_size, void* d_ws, size_t ws_size,
                              hipStream_t stream) {
  const float* fd  = (const float*)d_in[0];
  const float* fs  = (const float*)d_in[1];
  const float* W0  = (const float*)d_in[2];
  const float* Wdw = (const float*)d_in[3];
  const float* Wq  = (const float*)d_in[4];
  const float* Wk  = (const float*)d_in[5];
  const float* Wv  = (const float*)d_in[6];
  const float* Wp  = (const float*)d_in[7];
  const float* bp  = (const float*)d_in[8];
  const float* Wsp = (const float*)d_in[9];
  const float* w1d = (const float*)d_in[10];
  const float* w2d = (const float*)d_in[11];
  const float* w1s = (const float*)d_in[12];
  const float* w2s = (const float*)d_in[13];

  char* ws = (char*)d_ws;
  u16* x0b    = (u16*)(ws + 0);            // [B,N,256] 16.7MB; dead after dwconv
  u16* outcb  = x0b;                       // [B,256,N] (reuse)
  u16* xtb    = (u16*)(ws + 16777216);     // [B,N,256] 16.7MB; live to outc gemm
  u16* xtT    = (u16*)(ws + 33554432);     // [B,256,N] 16.7MB; dead after gram
  u16* part2  = (u16*)(ws + 50331648);     // [B][256][4096] hi/lo 16.8MB
  u16* S2     = (u16*)(ws + 67108864);     // [B,256,512] hi|lo 2.1MB
  float* araw = (float*)(ws + 69206016);   // [B,256,256] fp32 2.1MB
  u16* attnb  = (u16*)(ws + 71303168);     // [B,256,256] 1MB
  u16* m1t    = (u16*)(ws + 72351744);     // [B,256,256] 1MB
  u16* wfin   = (u16*)(ws + 73400320);     // [B,256,256] 1MB
  u16* w0b    = (u16*)(ws + 74448896);     // [256,512]
  u16* wqk8   = (u16*)(ws + 74711040);     // [512,4096] 4MB
  u16* wvtb   = (u16*)(ws + 78905344);     // [256,256]
  u16* wcb    = (u16*)(ws + 79036416);     // [256,256]
  float* bcb  = (float*)(ws + 79167488);   // 256
  float* dpart = (float*)(ws + 79168512);  // [4][B*512] fp32 64KB
  float* poolpart = (float*)(ws + 79234048); // [64][B,256] fp32 512KB
  float* gdp  = (float*)(ws + 79758336);
  float* gsp  = (float*)(ws + 79766528);
  float* od  = (float*)d_out;
  float* osg = od + 8388608;

  prep<<<dim3(2048, 4), 256, 0, stream>>>(W0, Wq, Wk, Wv, Wsp, Wp, bp,
                                          w0b, wqk8, wvtb, wcb, bcb);
  // fused concat+conv0: reads fd/fs once, writes x0
  conv0f<<<dim3(32, 8), 512, 0, stream>>>(fd, fs, w0b, x0b);
  dwconv3x3<<<4096, 256, 0, stream>>>(x0b, Wdw, xtb);
  btrans<<<dim3(128, 8, 8), dim3(32, 8), 0, stream>>>(xtb, xtT);
  // Gram: G_s[m,n] -> part2 hi/lo (EPI=3)   M=N=256 K=4096, split-K x8
  gemm_nt<u16, 0, false, 3><<<dim3(2, 2, 64), 256, 0, stream>>>(
      xtT, 1048576, 4096, xtT, 1048576, 4096,
      part2, 1048576, 0, 4096, nullptr, 512, 8, nullptr, nullptr, nullptr, nullptr);
  // SS = Wqk @ G via K-stacked hi/lo: A=wqk8 [512][4096], B=part2   M=512 N=256 K=4096
  gemm_nt<u16, 0, false, 1><<<dim3(4, 2, 8), 256, 0, stream>>>(
      wqk8, 0, 4096, part2, 1048576, 4096, S2, 131072, 0, 512, nullptr, 4096, 1,
      nullptr, Wq, Wk, dpart);
  // araw = Wk G Wq^T: A = wqk8 Wk-block (first 512 cols = [Wk|Wk]), B = S2 hi|lo
  gemm_nt<float, 0, false, 0><<<dim3(2, 2, 8), 256, 0, stream>>>(
      wqk8 + (long)256 * 4096, 0, 4096, S2, 131072, 512, araw, 65536, 0, 256,
      nullptr, 512, 1, nullptr, nullptr, nullptr, nullptr);
  softmax_g2<<<512, 256, 0, stream>>>(araw, dpart, attnb);
  // m1t[b,e,c] = sum_d WvT[e,d] attn[b,c,d]   M=N=256 K=256
  gemm_nt<u16, 0, false, 0><<<dim3(2, 2, 8), 256, 0, stream>>>(
      wvtb, 0, 256, attnb, 65536, 256, m1t, 65536, 0, 256, nullptr, 256, 1,
      nullptr, nullptr, nullptr, nullptr);
  // wfin[b,o,e] = sum_c Wc[o,c] m1t[b,e,c]   M=N=256 K=256
  gemm_nt<u16, 0, false, 0><<<dim3(2, 2, 8), 256, 0, stream>>>(
      wcb, 0, 256, m1t, 65536, 256, wfin, 65536, 0, 256, nullptr, 256, 1,
      nullptr, nullptr, nullptr, nullptr);
  // outc[b,o,n] = sum_e wfin[b,o,e] xt[b,n,e] + bc[o]   M=256 N=4096 K=256, +pool
  gemm_nt<u16, 2, true, 0><<<dim3(2, 32, 8), 256, 0, stream>>>(
      wfin, 65536, 256, xtb, 1048576, 256, outcb, 1048576, 0, 4096, bcb, 256, 1,
      poolpart, nullptr, nullptr, nullptr);
  se_gates<<<8, 256, 0, stream>>>(poolpart, w1d, w2d, w1s, w2s, gdp, gsp);
  fuse_out<<<4096, 256, 0, stream>>>(outcb, gdp, gsp, fd, fs, od, osg);
}

// Round 9
// 174.780 us; speedup vs baseline: 1.3146x; 1.3146x over previous
//
#include <hip/hip_runtime.h>
#include <cstdint>

#define DEVI __device__ __forceinline__

using fx4 = __attribute__((ext_vector_type(4))) float;
using bf8 = __attribute__((ext_vector_type(8))) __bf16;
using s8v = __attribute__((ext_vector_type(8))) short;
using s4v = __attribute__((ext_vector_type(4))) short;
typedef unsigned short u16;
typedef unsigned int u32;

DEVI float b2f(u16 u) { return __builtin_bit_cast(float, (u32)u << 16); }
DEVI u16 f2b(float f) {
  u32 u = __builtin_bit_cast(u32, f);
  return (u16)((u + 0x7fffu + ((u >> 16) & 1u)) >> 16);
}

// async global->LDS, 16B per lane, dest = wave-uniform base + lane*16
#define GLOAD(g, l)                                                          \
  __builtin_amdgcn_global_load_lds(                                          \
      (const __attribute__((address_space(1))) unsigned int*)(g),            \
      (__attribute__((address_space(3))) unsigned int*)(l), 16, 0, 0)

// ---- weight prep: W0->bf16; wqk2=[Wq|Wq ; Wk|Wk]; WvT; Wc=Wsp@Wp, bc=Wsp@bp ----
__global__ __launch_bounds__(256) void prep(const float* __restrict__ W0,
                                            const float* __restrict__ Wq,
                                            const float* __restrict__ Wk,
                                            const float* __restrict__ Wv,
                                            const float* __restrict__ Wsp,
                                            const float* __restrict__ Wp,
                                            const float* __restrict__ bp,
                                            u16* __restrict__ w0b,
                                            u16* __restrict__ wqk2,
                                            u16* __restrict__ wvtb,
                                            u16* __restrict__ wcb,
                                            float* __restrict__ bcb) {
  __shared__ float row[256];
  __shared__ float red[4];
  const int y = blockIdx.y;
  const int t = threadIdx.x;
  if (y == 0) {
    const int i = blockIdx.x * 256 + t;
    if (i < 131072) w0b[i] = f2b(W0[i]);
  } else if (y == 1) {
    const int i = blockIdx.x * 256 + t;
    // wqk2 is [512][512] = 262144 elements. (R7/R8 bug: bound was 524288,
    // a 2x overrun that trampled wvtb/wcb/bcb.)
    if (i < 262144) {
      const int r = i >> 9, c = i & 511;
      const float* src = (r < 256) ? Wq : Wk;
      wqk2[i] = f2b(src[((r & 255) << 8) + (c & 255)]);
    }
  } else if (y == 2) {
    const int i = blockIdx.x * 256 + t;
    if (i < 65536) {
      const int e = i >> 8, d = i & 255;
      wvtb[i] = f2b(Wv[d * 256 + e]);          // WvT[e,d] = Wv[d,e]
    }
  } else {
    if (blockIdx.x >= 256) return;
    const int o = blockIdx.x;
    row[t] = Wsp[o * 256 + t];
    __syncthreads();
    float acc = 0.f;
    for (int c = 0; c < 256; ++c) acc += row[c] * Wp[c * 256 + t];
    wcb[o * 256 + t] = f2b(acc);
    float pb = row[t] * bp[t];
#pragma unroll
    for (int m = 32; m > 0; m >>= 1) pb += __shfl_xor(pb, m);
    if ((t & 63) == 0) red[t >> 6] = pb;
    __syncthreads();
    if (t == 0) bcb[o] = red[0] + red[1] + red[2] + red[3];
  }
}

// ---- fused concat+1x1 conv: x0[b,n,o] = sum_c [fd;fs][b,c,n] * W0[o,c] ----
__global__ __launch_bounds__(512) void conv0f(const float* __restrict__ fd,
                                              const float* __restrict__ fs,
                                              const u16* __restrict__ w0b,
                                              u16* __restrict__ x0) {
  __shared__ u16 tmp[64 * 132];     // [c][n], pad 4
  __shared__ u16 ldsA[128 * 64];    // [n][c] chunk-swizzled
  __shared__ u16 ldsB[256 * 64];    // [o][c] linear (GLOAD)
  const int b = blockIdx.y;
  const int bm = blockIdx.x * 128;
  const int t = threadIdx.x;
  const int wid = t >> 6, lane = t & 63;
  const int wm = wid >> 2, wn = wid & 3;
  fx4 acc[4][4] = {};
  for (int kt = 0; kt < 512; kt += 64) {
#pragma unroll
    for (int i = 0; i < 4; ++i) {
      const int r = i * 64 + (t >> 3);
      const int kq = (t & 7) ^ (r & 7);
      GLOAD(w0b + (long)r * 512 + kt + kq * 8, &ldsB[i * 4096 + wid * 512]);
    }
    const float* src = ((kt < 256) ? fd : fs) + ((long)b * 256 + (kt & 255)) * 4096L + bm;
#pragma unroll
    for (int p = 0; p < 4; ++p) {
      const int c = (t >> 5) + p * 16;
      const int n4 = (t & 31) * 4;
      const fx4 v = *(const fx4*)&src[(long)c * 4096 + n4];
      s4v pk;
#pragma unroll
      for (int j = 0; j < 4; ++j) pk[j] = (short)f2b(v[j]);
      *(s4v*)&tmp[c * 132 + n4] = pk;
    }
    __syncthreads();
#pragma unroll
    for (int pass = 0; pass < 2; ++pass) {
      const int n = t & 127;
      const int g = (t >> 7) + pass * 4;
      s8v pk;
#pragma unroll
      for (int j = 0; j < 8; ++j) pk[j] = (short)tmp[(g * 8 + j) * 132 + n];
      *(s8v*)&ldsA[n * 64 + ((g ^ (n & 7)) * 8)] = pk;
    }
    __syncthreads();
#pragma unroll
    for (int ko = 0; ko < 2; ++ko) {
      bf8 af[4], bfr[4];
      const int kq = ko * 4 + (lane >> 4);
#pragma unroll
      for (int f = 0; f < 4; ++f) {
        const int ar = wm * 64 + f * 16 + (lane & 15);
        af[f] = *(const bf8*)&ldsA[ar * 64 + ((kq ^ (ar & 7)) * 8)];
        const int br = wn * 64 + f * 16 + (lane & 15);
        bfr[f] = *(const bf8*)&ldsB[br * 64 + ((kq ^ (br & 7)) * 8)];
      }
#pragma unroll
      for (int fm = 0; fm < 4; ++fm)
#pragma unroll
        for (int fn = 0; fn < 4; ++fn)
          acc[fm][fn] = __builtin_amdgcn_mfma_f32_16x16x32_bf16(af[fm], bfr[fn], acc[fm][fn], 0, 0, 0);
    }
    __syncthreads();
  }
#pragma unroll
  for (int fm = 0; fm < 4; ++fm) {
    const int m0 = wm * 64 + fm * 16 + ((lane >> 4) << 2);
#pragma unroll
    for (int fn = 0; fn < 4; ++fn) {
      const int o = wn * 64 + fn * 16 + (lane & 15);
#pragma unroll
      for (int r = 0; r < 4; ++r)
        x0[((long)b << 20) + (long)(bm + m0 + r) * 256 + o] = f2b(acc[fm][fn][r]);
    }
  }
}

// ---- bf16 NT GEMM: C[m,n] = sum_k A[m,k]*B[n,k] ----
// BIAS: 0 none, 2 bias[m]. POOL: per-tile row sums.
// EPI: 0 normal C write; 1 = S2 hi/lo write (rows<256) + diag partials.
template <typename OT, int BIAS, bool POOL, int EPI>
__global__ __launch_bounds__(256) void gemm_nt(
    const u16* __restrict__ A, long sA, int lda,
    const u16* __restrict__ B, long sB, int ldb,
    OT* __restrict__ C, long sC, long sCs, int ldc,
    const float* __restrict__ bias, int Keff, int ksplit,
    float* __restrict__ poolpart,
    const float* __restrict__ wqf, const float* __restrict__ wkf,
    float* __restrict__ dpart) {
  __shared__ u16 ldsA[128 * 64];
  __shared__ u16 ldsB[128 * 64];
  const int z = blockIdx.z;
  const int bb = z / ksplit;
  const int ss = z - bb * ksplit;
  const int bm = blockIdx.x * 128;
  const int bn = blockIdx.y * 128;
  const u16* Ab = A + bb * sA + (long)ss * Keff + (long)bm * lda;
  const u16* Bb = B + bb * sB + (long)ss * Keff + (long)bn * ldb;
  const int tid = threadIdx.x;
  const int wid = tid >> 6;
  const int lane = tid & 63;
  const int wm = wid >> 1, wn = wid & 1;
  const int srow = tid >> 3;
  const int slot = tid & 7;

  fx4 acc[4][4] = {};
  for (int kt = 0; kt < Keff; kt += 64) {
#pragma unroll
    for (int i = 0; i < 4; ++i) {
      const int row = i * 32 + srow;
      const int kq = slot ^ (row & 7);
      GLOAD(Ab + (long)row * lda + kt + kq * 8, &ldsA[i * 2048 + wid * 512]);
      GLOAD(Bb + (long)row * ldb + kt + kq * 8, &ldsB[i * 2048 + wid * 512]);
    }
    __syncthreads();
#pragma unroll
    for (int ko = 0; ko < 2; ++ko) {
      bf8 af[4], bfr[4];
      const int kq = ko * 4 + (lane >> 4);
#pragma unroll
      for (int f = 0; f < 4; ++f) {
        const int ar = wm * 64 + f * 16 + (lane & 15);
        af[f] = *(const bf8*)&ldsA[ar * 64 + ((kq ^ (ar & 7)) * 8)];
        const int br = wn * 64 + f * 16 + (lane & 15);
        bfr[f] = *(const bf8*)&ldsB[br * 64 + ((kq ^ (br & 7)) * 8)];
      }
#pragma unroll
      for (int fm = 0; fm < 4; ++fm)
#pragma unroll
        for (int fn = 0; fn < 4; ++fn)
          acc[fm][fn] = __builtin_amdgcn_mfma_f32_16x16x32_bf16(af[fm], bfr[fn], acc[fm][fn], 0, 0, 0);
    }
    __syncthreads();
  }
  if constexpr (EPI == 1) {
    u16* S2b = (u16*)C + bb * sC;
    float dp[4][4];
#pragma unroll
    for (int fm = 0; fm < 4; ++fm)
#pragma unroll
      for (int r = 0; r < 4; ++r) dp[fm][r] = 0.f;
#pragma unroll
    for (int fm = 0; fm < 4; ++fm) {
      const int m0 = bm + wm * 64 + fm * 16 + ((lane >> 4) << 2);
#pragma unroll
      for (int fn = 0; fn < 4; ++fn) {
        const int n0 = bn + wn * 64 + fn * 16 + (lane & 15);
#pragma unroll
        for (int r = 0; r < 4; ++r) {
          const float v = acc[fm][fn][r];
          const int m = m0 + r;
          if (m < 256) {
            const u16 hi = f2b(v);
            S2b[(long)m * 512 + n0] = hi;
            S2b[(long)m * 512 + 256 + n0] = f2b(v - b2f(hi));
          }
          const float* wr = (m < 256) ? (wqf + (long)m * 256) : (wkf + (long)(m - 256) * 256);
          dp[fm][r] += v * wr[n0];
        }
      }
    }
#pragma unroll
    for (int fm = 0; fm < 4; ++fm)
#pragma unroll
      for (int r = 0; r < 4; ++r) {
        float s = dp[fm][r];
        s += __shfl_xor(s, 1); s += __shfl_xor(s, 2);
        s += __shfl_xor(s, 4); s += __shfl_xor(s, 8);
        if ((lane & 15) == 0) {
          const int m = bm + wm * 64 + fm * 16 + ((lane >> 4) << 2) + r;
          dpart[(long)(blockIdx.y * 2 + wn) * 4096 + bb * 512 + m] = s;
        }
      }
    return;
  }
  OT* Cb = C + bb * sC + ss * sCs;
  float pr[4][4];
  if (POOL) {
#pragma unroll
    for (int fm = 0; fm < 4; ++fm)
#pragma unroll
      for (int r = 0; r < 4; ++r) pr[fm][r] = 0.f;
  }
#pragma unroll
  for (int fm = 0; fm < 4; ++fm) {
    const int m0 = bm + wm * 64 + fm * 16 + ((lane >> 4) << 2);
#pragma unroll
    for (int fn = 0; fn < 4; ++fn) {
      const int n0 = bn + wn * 64 + fn * 16 + (lane & 15);
#pragma unroll
      for (int r = 0; r < 4; ++r) {
        float v = acc[fm][fn][r];
        if (BIAS == 2) v += bias[m0 + r];
        if constexpr (sizeof(OT) == 2) Cb[(long)(m0 + r) * ldc + n0] = (OT)f2b(v);
        else Cb[(long)(m0 + r) * ldc + n0] = v;
        if (POOL) pr[fm][r] += v;
      }
    }
  }
  if (POOL) {
#pragma unroll
    for (int fm = 0; fm < 4; ++fm)
#pragma unroll
      for (int r = 0; r < 4; ++r) {
        float s = pr[fm][r];
        s += __shfl_xor(s, 1); s += __shfl_xor(s, 2);
        s += __shfl_xor(s, 4); s += __shfl_xor(s, 8);
        if ((lane & 15) == 0) {
          const int o = bm + wm * 64 + fm * 16 + ((lane >> 4) << 2) + r;
          poolpart[(long)(blockIdx.y * 2 + wn) * 2048 + bb * 256 + o] = s;
        }
      }
  }
}

// ---- depthwise 3x3 SAME, [B,N,C] bf16 layout ----
__global__ __launch_bounds__(256) void dwconv3x3(const u16* __restrict__ x,
                                                 const float* __restrict__ wdw,
                                                 u16* __restrict__ y) {
  __shared__ float w[9][256];
  const int t = threadIdx.x;
  for (int i = t; i < 2304; i += 256) w[i % 9][i / 9] = wdw[i];
  __syncthreads();
  const int nb = blockIdx.x;
  const int b = nb >> 9;
  const int n0 = (nb & 511) << 3;
  const int tn = t >> 5;
  const int tc = (t & 31) << 3;
  const int n = n0 + tn;
  const int hh = n >> 6, ww2 = n & 63;
  const u16* base = x + ((long)b << 20);
  float acc[8] = {0.f, 0.f, 0.f, 0.f, 0.f, 0.f, 0.f, 0.f};
#pragma unroll
  for (int ky = 0; ky < 3; ++ky) {
    const int hy = hh + ky - 1;
    if ((unsigned)hy >= 64u) continue;
#pragma unroll
    for (int kx = 0; kx < 3; ++kx) {
      const int wx = ww2 + kx - 1;
      if ((unsigned)wx >= 64u) continue;
      const s8v v = *(const s8v*)&base[(((hy << 6) + wx) << 8) + tc];
      const int kk = ky * 3 + kx;
      const fx4 wa = *(const fx4*)&w[kk][tc];
      const fx4 wb = *(const fx4*)&w[kk][tc + 4];
#pragma unroll
      for (int j = 0; j < 4; ++j) {
        acc[j] += wa[j] * b2f((u16)v[j]);
        acc[4 + j] += wb[j] * b2f((u16)v[4 + j]);
      }
    }
  }
  s8v o;
#pragma unroll
  for (int j = 0; j < 8; ++j) o[j] = (short)f2b(acc[j]);
  *(s8v*)&y[((long)b << 20) + ((long)n << 8) + tc] = o;
}

// ---- bf16 transpose: xt [B,4096,256] -> xtT [B,256,4096] ----
__global__ void btrans(const u16* __restrict__ x, u16* __restrict__ y) {
  __shared__ u16 t[32][34];
  const int b = blockIdx.z;
  const int n0 = blockIdx.x * 32;
  const int c0 = blockIdx.y * 32;
  const int tx = threadIdx.x, ty = threadIdx.y;
  const u16* sp = x + (long)b * 1048576 + (long)n0 * 256 + c0;
#pragma unroll
  for (int j = 0; j < 4; ++j) {
    int i = ty + j * 8;
    t[i][tx] = sp[(long)i * 256 + tx];
  }
  __syncthreads();
  u16* op = y + (long)b * 1048576 + (long)c0 * 4096 + n0;
#pragma unroll
  for (int j = 0; j < 4; ++j) {
    int r = ty + j * 8;
    op[(long)r * 4096 + tx] = t[tx][r];
  }
}

// ---- sum Gram split-K partials (8) -> hi/lo bf16 G2 [B,256,512] ----
__global__ __launch_bounds__(256) void gsplit(const float* __restrict__ part,
                                              u16* __restrict__ G2) {
  const int i4 = (blockIdx.x * 256 + threadIdx.x) * 4;    // over 524288
  fx4 s = {0.f, 0.f, 0.f, 0.f};
#pragma unroll
  for (int ss = 0; ss < 8; ++ss) s += *(const fx4*)(part + (long)ss * 524288 + i4);
  const int b = i4 >> 16, rem = i4 & 65535, e = rem >> 8, c0 = rem & 255;
  u16* d = G2 + (long)b * 131072 + (long)e * 512 + c0;
  s4v hi, lo;
#pragma unroll
  for (int j = 0; j < 4; ++j) {
    u16 h = f2b(s[j]);
    hi[j] = (short)h;
    lo[j] = (short)f2b(s[j] - b2f(h));
  }
  *(s4v*)d = hi;
  *(s4v*)(d + 256) = lo;
}

// ---- finalize rinv from diag partials + row softmax over d -> bf16 attn ----
__global__ __launch_bounds__(256) void softmax_g2(const float* __restrict__ araw,
                                                  const float* __restrict__ dpart,
                                                  u16* __restrict__ out) {
  const int wid = threadIdx.x >> 6, lane = threadIdx.x & 63;
  const int t = threadIdx.x;
  const int b = blockIdx.x >> 6;
  __shared__ float rq[256];
  float dq = dpart[b * 512 + t] + dpart[4096 + b * 512 + t] +
             dpart[8192 + b * 512 + t] + dpart[12288 + b * 512 + t];
  rq[t] = 1.f / fmaxf(sqrtf(fmaxf(dq, 0.f)), 1e-12f);
  __syncthreads();
  const long row = (long)blockIdx.x * 4 + wid;   // b*256 + c
  const int c = (int)(row & 255);
  const int ki = b * 512 + 256 + c;
  float dk = dpart[ki] + dpart[4096 + ki] + dpart[8192 + ki] + dpart[12288 + ki];
  const float rk = 1.f / fmaxf(sqrtf(fmaxf(dk, 0.f)), 1e-12f);
  fx4 v = ((const fx4*)(araw + row * 256))[lane];
  v[0] *= rk * rq[lane * 4];     v[1] *= rk * rq[lane * 4 + 1];
  v[2] *= rk * rq[lane * 4 + 2]; v[3] *= rk * rq[lane * 4 + 3];
  float m = fmaxf(fmaxf(v[0], v[1]), fmaxf(v[2], v[3]));
#pragma unroll
  for (int o = 32; o > 0; o >>= 1) m = fmaxf(m, __shfl_xor(m, o));
  float e0 = __expf(v[0] - m), e1 = __expf(v[1] - m);
  float e2 = __expf(v[2] - m), e3 = __expf(v[3] - m);
  float s4 = e0 + e1 + e2 + e3;
#pragma unroll
  for (int o = 32; o > 0; o >>= 1) s4 += __shfl_xor(s4, o);
  const float inv = 1.f / s4;
  u16* op = out + row * 256 + lane * 4;
  op[0] = f2b(e0 * inv); op[1] = f2b(e1 * inv);
  op[2] = f2b(e2 * inv); op[3] = f2b(e3 * inv);
}

// ---- SE gates: sum pooled partials + 2-layer MLP ----
__global__ __launch_bounds__(256) void se_gates(const float* __restrict__ poolpart,
                                                const float* __restrict__ w1d, const float* __restrict__ w2d,
                                                const float* __restrict__ w1s, const float* __restrict__ w2s,
                                                float* __restrict__ gd, float* __restrict__ gs) {
  const int b = blockIdx.x;
  const int t = threadIdx.x;
  __shared__ float p[256], hd[16], hs[16];
  float s = 0.f;
#pragma unroll 8
  for (int sl = 0; sl < 64; ++sl) s += poolpart[(long)sl * 2048 + b * 256 + t];
  p[t] = s * (1.f / 4096.f);
  __syncthreads();
  if (t < 16) {
    float ad = 0.f, as2 = 0.f;
    for (int j = 0; j < 256; ++j) {
      ad += w1d[t * 256 + j] * p[j];
      as2 += w1s[t * 256 + j] * p[j];
    }
    hd[t] = fmaxf(ad, 0.f);
    hs[t] = fmaxf(as2, 0.f);
  }
  __syncthreads();
  float ad = 0.f, as2 = 0.f;
#pragma unroll
  for (int r = 0; r < 16; ++r) {
    ad += w2d[t * 16 + r] * hd[r];
    as2 += w2s[t * 16 + r] * hs[r];
  }
  gd[b * 256 + t] = 1.f / (1.f + __expf(-ad));
  gs[b * 256 + t] = 1.f / (1.f + __expf(-as2));
}

// ---- final: out = outc(bf16)*gate + fp32 residual (layout-aligned) ----
__global__ __launch_bounds__(256) void fuse_out(const u16* __restrict__ oc,
                                                const float* __restrict__ gd, const float* __restrict__ gs,
                                                const float* __restrict__ fd, const float* __restrict__ fs,
                                                float* __restrict__ od, float* __restrict__ os) {
  const long i = ((long)blockIdx.x * 256 + threadIdx.x) * 8;
  const long bc = i >> 12;
  const float gdv = gd[bc], gsv = gs[bc];
  const s8v c8 = *(const s8v*)&oc[i];
  const fx4 a0 = *(const fx4*)(fd + i), a1 = *(const fx4*)(fd + i + 4);
  const fx4 s0 = *(const fx4*)(fs + i), s1 = *(const fx4*)(fs + i + 4);
  fx4 d0, d1, e0, e1;
#pragma unroll
  for (int j = 0; j < 4; ++j) {
    const float cl = b2f((u16)c8[j]);
    const float ch = b2f((u16)c8[4 + j]);
    d0[j] = cl * gdv + a0[j]; d1[j] = ch * gdv + a1[j];
    e0[j] = cl * gsv + s0[j]; e1[j] = ch * gsv + s1[j];
  }
  *(fx4*)(od + i) = d0; *(fx4*)(od + i + 4) = d1;
  *(fx4*)(os + i) = e0; *(fx4*)(os + i + 4) = e1;
}

extern "C" void kernel_launch(void* const* d_in, const int* in_sizes, int n_in,
                              void* d_out, int out_size, void* d_ws, size_t ws_size,
                              hipStream_t stream) {
  const float* fd  = (const float*)d_in[0];
  const float* fs  = (const float*)d_in[1];
  const float* W0  = (const float*)d_in[2];
  const float* Wdw = (const float*)d_in[3];
  const float* Wq  = (const float*)d_in[4];
  const float* Wk  = (const float*)d_in[5];
  const float* Wv  = (const float*)d_in[6];
  const float* Wp  = (const float*)d_in[7];
  const float* bp  = (const float*)d_in[8];
  const float* Wsp = (const float*)d_in[9];
  const float* w1d = (const float*)d_in[10];
  const float* w2d = (const float*)d_in[11];
  const float* w1s = (const float*)d_in[12];
  const float* w2s = (const float*)d_in[13];

  char* ws = (char*)d_ws;
  u16* x0b    = (u16*)(ws + 0);            // [B,N,256] 16.7MB; dead after dwconv
  u16* outcb  = x0b;                       // [B,256,N] (reuse)
  u16* xtb    = (u16*)(ws + 16777216);     // [B,N,256] 16.7MB; live to outc gemm
  u16* xtT    = (u16*)(ws + 33554432);     // [B,256,N] 16.7MB; dead after gram
  float* part = (float*)(ws + 50331648);   // [8][B,256,256] fp32 16.7MB
  u16* G2     = (u16*)(ws + 67108864);     // [B,256,512] hi|lo 2.1MB
  u16* S2     = (u16*)(ws + 69206016);     // [B,256,512] hi|lo 2.1MB
  float* araw = (float*)(ws + 71303168);   // [B,256,256] fp32 2.1MB
  u16* attnb  = (u16*)(ws + 73400320);     // [B,256,256] 1MB
  u16* m1t    = (u16*)(ws + 74448896);     // [B,256,256] 1MB
  u16* wfin   = (u16*)(ws + 75497472);     // [B,256,256] 1MB
  u16* w0b    = (u16*)(ws + 76546048);     // [256,512] 256KB
  u16* wqk2   = (u16*)(ws + 76808192);     // [512,512] 512KB
  u16* wvtb   = (u16*)(ws + 77332480);     // [256,256] 128KB
  u16* wcb    = (u16*)(ws + 77463552);     // [256,256] 128KB
  float* bcb  = (float*)(ws + 77594624);   // 256
  float* dpart = (float*)(ws + 77595648);  // [4][B*512] fp32 64KB
  float* poolpart = (float*)(ws + 77661184); // [64][B,256] fp32 512KB
  float* gdp  = (float*)(ws + 78185472);
  float* gsp  = (float*)(ws + 78193664);
  float* od  = (float*)d_out;
  float* osg = od + 8388608;

  prep<<<dim3(2048, 4), 256, 0, stream>>>(W0, Wq, Wk, Wv, Wsp, Wp, bp,
                                          w0b, wqk2, wvtb, wcb, bcb);
  conv0f<<<dim3(32, 8), 512, 0, stream>>>(fd, fs, w0b, x0b);
  dwconv3x3<<<4096, 256, 0, stream>>>(x0b, Wdw, xtb);
  btrans<<<dim3(128, 8, 8), dim3(32, 8), 0, stream>>>(xtb, xtT);
  // Gram: G[b,c,e] = sum_n xtT[b,c,n] xtT[b,e,n]   M=N=256 K=4096, split-K x8
  gemm_nt<float, 0, false, 0><<<dim3(2, 2, 64), 256, 0, stream>>>(
      xtT, 1048576, 4096, xtT, 1048576, 4096,
      part, 65536, 524288, 256, nullptr, 512, 8, nullptr, nullptr, nullptr, nullptr);
  gsplit<<<512, 256, 0, stream>>>(part, G2);
  // SS = Wqk @ G  (M=512 N=256 K=512 hi|lo) with fused S2-split + diag partials
  gemm_nt<u16, 0, false, 1><<<dim3(4, 2, 8), 256, 0, stream>>>(
      wqk2, 0, 512, G2, 131072, 512, S2, 131072, 0, 512, nullptr, 512, 1,
      nullptr, Wq, Wk, dpart);
  // araw = Wk G Wq^T: A=[Wk|Wk], B=S2 hi|lo   M=N=256 K=512
  gemm_nt<float, 0, false, 0><<<dim3(2, 2, 8), 256, 0, stream>>>(
      wqk2 + 131072, 0, 512, S2, 131072, 512, araw, 65536, 0, 256, nullptr, 512, 1,
      nullptr, nullptr, nullptr, nullptr);
  softmax_g2<<<512, 256, 0, stream>>>(araw, dpart, attnb);
  // m1t[b,e,c] = sum_d WvT[e,d] attn[b,c,d]   M=N=256 K=256
  gemm_nt<u16, 0, false, 0><<<dim3(2, 2, 8), 256, 0, stream>>>(
      wvtb, 0, 256, attnb, 65536, 256, m1t, 65536, 0, 256, nullptr, 256, 1,
      nullptr, nullptr, nullptr, nullptr);
  // wfin[b,o,e] = sum_c Wc[o,c] m1t[b,e,c]   M=N=256 K=256
  gemm_nt<u16, 0, false, 0><<<dim3(2, 2, 8), 256, 0, stream>>>(
      wcb, 0, 256, m1t, 65536, 256, wfin, 65536, 0, 256, nullptr, 256, 1,
      nullptr, nullptr, nullptr, nullptr);
  // outc[b,o,n] = sum_e wfin[b,o,e] xt[b,n,e] + bc[o]   M=256 N=4096 K=256, +pool
  gemm_nt<u16, 2, true, 0><<<dim3(2, 32, 8), 256, 0, stream>>>(
      wfin, 65536, 256, xtb, 1048576, 256, outcb, 1048576, 0, 4096, bcb, 256, 1,
      poolpart, nullptr, nullptr, nullptr);
  se_gates<<<8, 256, 0, stream>>>(poolpart, w1d, w2d, w1s, w2s, gdp, gsp);
  fuse_out<<<4096, 256, 0, stream>>>(outcb, gdp, gsp, fd, fs, od, osg);
}

// Round 10
// 168.662 us; speedup vs baseline: 1.3623x; 1.0363x over previous
//
#include <hip/hip_runtime.h>
#include <cstdint>

#define DEVI __device__ __forceinline__

using fx4 = __attribute__((ext_vector_type(4))) float;
using bf8 = __attribute__((ext_vector_type(8))) __bf16;
using s8v = __attribute__((ext_vector_type(8))) short;
using s4v = __attribute__((ext_vector_type(4))) short;
typedef unsigned short u16;
typedef unsigned int u32;

DEVI float b2f(u16 u) { return __builtin_bit_cast(float, (u32)u << 16); }
DEVI u16 f2b(float f) {
  u32 u = __builtin_bit_cast(u32, f);
  return (u16)((u + 0x7fffu + ((u >> 16) & 1u)) >> 16);
}

// async global->LDS, 16B per lane, dest = wave-uniform base + lane*16
#define GLOAD(g, l)                                                          \
  __builtin_amdgcn_global_load_lds(                                          \
      (const __attribute__((address_space(1))) unsigned int*)(g),            \
      (__attribute__((address_space(3))) unsigned int*)(l), 16, 0, 0)

// ---- weight prep: W0->bf16; wqk2=[Wq|Wq ; Wk|Wk]; WvT; Wc=Wsp@Wp, bc=Wsp@bp ----
__global__ __launch_bounds__(256) void prep(const float* __restrict__ W0,
                                            const float* __restrict__ Wq,
                                            const float* __restrict__ Wk,
                                            const float* __restrict__ Wv,
                                            const float* __restrict__ Wsp,
                                            const float* __restrict__ Wp,
                                            const float* __restrict__ bp,
                                            u16* __restrict__ w0b,
                                            u16* __restrict__ wqk2,
                                            u16* __restrict__ wvtb,
                                            u16* __restrict__ wcb,
                                            float* __restrict__ bcb) {
  __shared__ float row[256];
  __shared__ float red[4];
  const int y = blockIdx.y;
  const int t = threadIdx.x;
  if (y == 0) {
    const int i = blockIdx.x * 256 + t;
    if (i < 131072) w0b[i] = f2b(W0[i]);
  } else if (y == 1) {
    const int i = blockIdx.x * 256 + t;
    // wqk2 is [512][512] = 262144 elements (R7/R8 bug was a 2x overrun here).
    if (i < 262144) {
      const int r = i >> 9, c = i & 511;
      const float* src = (r < 256) ? Wq : Wk;
      wqk2[i] = f2b(src[((r & 255) << 8) + (c & 255)]);
    }
  } else if (y == 2) {
    const int i = blockIdx.x * 256 + t;
    if (i < 65536) {
      const int e = i >> 8, d = i & 255;
      wvtb[i] = f2b(Wv[d * 256 + e]);          // WvT[e,d] = Wv[d,e]
    }
  } else {
    if (blockIdx.x >= 256) return;
    const int o = blockIdx.x;
    row[t] = Wsp[o * 256 + t];
    __syncthreads();
    float acc = 0.f;
    for (int c = 0; c < 256; ++c) acc += row[c] * Wp[c * 256 + t];
    wcb[o * 256 + t] = f2b(acc);
    float pb = row[t] * bp[t];
#pragma unroll
    for (int m = 32; m > 0; m >>= 1) pb += __shfl_xor(pb, m);
    if ((t & 63) == 0) red[t >> 6] = pb;
    __syncthreads();
    if (t == 0) bcb[o] = red[0] + red[1] + red[2] + red[3];
  }
}

// ---- fused concat+1x1 conv: x0[b,n,o] = sum_c [fd;fs][b,c,n] * W0[o,c] ----
__global__ __launch_bounds__(512) void conv0f(const float* __restrict__ fd,
                                              const float* __restrict__ fs,
                                              const u16* __restrict__ w0b,
                                              u16* __restrict__ x0) {
  __shared__ u16 tmp[64 * 132];     // [c][n], pad 4
  __shared__ u16 ldsA[128 * 64];    // [n][c] chunk-swizzled
  __shared__ u16 ldsB[256 * 64];    // [o][c] linear (GLOAD)
  const int b = blockIdx.y;
  const int bm = blockIdx.x * 128;
  const int t = threadIdx.x;
  const int wid = t >> 6, lane = t & 63;
  const int wm = wid >> 2, wn = wid & 3;
  fx4 acc[4][4] = {};
  for (int kt = 0; kt < 512; kt += 64) {
#pragma unroll
    for (int i = 0; i < 4; ++i) {
      const int r = i * 64 + (t >> 3);
      const int kq = (t & 7) ^ (r & 7);
      GLOAD(w0b + (long)r * 512 + kt + kq * 8, &ldsB[i * 4096 + wid * 512]);
    }
    const float* src = ((kt < 256) ? fd : fs) + ((long)b * 256 + (kt & 255)) * 4096L + bm;
#pragma unroll
    for (int p = 0; p < 4; ++p) {
      const int c = (t >> 5) + p * 16;
      const int n4 = (t & 31) * 4;
      const fx4 v = *(const fx4*)&src[(long)c * 4096 + n4];
      s4v pk;
#pragma unroll
      for (int j = 0; j < 4; ++j) pk[j] = (short)f2b(v[j]);
      *(s4v*)&tmp[c * 132 + n4] = pk;
    }
    __syncthreads();
#pragma unroll
    for (int pass = 0; pass < 2; ++pass) {
      const int n = t & 127;
      const int g = (t >> 7) + pass * 4;
      s8v pk;
#pragma unroll
      for (int j = 0; j < 8; ++j) pk[j] = (short)tmp[(g * 8 + j) * 132 + n];
      *(s8v*)&ldsA[n * 64 + ((g ^ (n & 7)) * 8)] = pk;
    }
    __syncthreads();
#pragma unroll
    for (int ko = 0; ko < 2; ++ko) {
      bf8 af[4], bfr[4];
      const int kq = ko * 4 + (lane >> 4);
#pragma unroll
      for (int f = 0; f < 4; ++f) {
        const int ar = wm * 64 + f * 16 + (lane & 15);
        af[f] = *(const bf8*)&ldsA[ar * 64 + ((kq ^ (ar & 7)) * 8)];
        const int br = wn * 64 + f * 16 + (lane & 15);
        bfr[f] = *(const bf8*)&ldsB[br * 64 + ((kq ^ (br & 7)) * 8)];
      }
#pragma unroll
      for (int fm = 0; fm < 4; ++fm)
#pragma unroll
        for (int fn = 0; fn < 4; ++fn)
          acc[fm][fn] = __builtin_amdgcn_mfma_f32_16x16x32_bf16(af[fm], bfr[fn], acc[fm][fn], 0, 0, 0);
    }
    __syncthreads();
  }
#pragma unroll
  for (int fm = 0; fm < 4; ++fm) {
    const int m0 = wm * 64 + fm * 16 + ((lane >> 4) << 2);
#pragma unroll
    for (int fn = 0; fn < 4; ++fn) {
      const int o = wn * 64 + fn * 16 + (lane & 15);
#pragma unroll
      for (int r = 0; r < 4; ++r)
        x0[((long)b << 20) + (long)(bm + m0 + r) * 256 + o] = f2b(acc[fm][fn][r]);
    }
  }
}

// ---- bf16 NT GEMM: C[m,n] = sum_k A[m,k]*B[n,k] ----
// EPI: 0 normal; 1 = S2 hi/lo (rows<256) + diag partials;
//      4 = dual-gated residual write: od/os = (acc+bias[m])*g +/- residual.
//      (EPI=4 arg mapping: wqf=fd, wkf=fs, dpart=gd, poolpart=gs, bias=bc)
template <typename OT, int BIAS, int EPI>
__global__ __launch_bounds__(256) void gemm_nt(
    const u16* __restrict__ A, long sA, int lda,
    const u16* __restrict__ B, long sB, int ldb,
    OT* __restrict__ C, long sC, long sCs, int ldc,
    const float* __restrict__ bias, int Keff, int ksplit,
    const float* __restrict__ wqf, const float* __restrict__ wkf,
    float* __restrict__ dpart, float* __restrict__ poolpart) {
  __shared__ u16 ldsA[128 * 64];
  __shared__ u16 ldsB[128 * 64];
  const int z = blockIdx.z;
  const int bb = z / ksplit;
  const int ss = z - bb * ksplit;
  const int bm = blockIdx.x * 128;
  const int bn = blockIdx.y * 128;
  const u16* Ab = A + bb * sA + (long)ss * Keff + (long)bm * lda;
  const u16* Bb = B + bb * sB + (long)ss * Keff + (long)bn * ldb;
  const int tid = threadIdx.x;
  const int wid = tid >> 6;
  const int lane = tid & 63;
  const int wm = wid >> 1, wn = wid & 1;
  const int srow = tid >> 3;
  const int slot = tid & 7;

  fx4 acc[4][4] = {};
  for (int kt = 0; kt < Keff; kt += 64) {
#pragma unroll
    for (int i = 0; i < 4; ++i) {
      const int row = i * 32 + srow;
      const int kq = slot ^ (row & 7);
      GLOAD(Ab + (long)row * lda + kt + kq * 8, &ldsA[i * 2048 + wid * 512]);
      GLOAD(Bb + (long)row * ldb + kt + kq * 8, &ldsB[i * 2048 + wid * 512]);
    }
    __syncthreads();
#pragma unroll
    for (int ko = 0; ko < 2; ++ko) {
      bf8 af[4], bfr[4];
      const int kq = ko * 4 + (lane >> 4);
#pragma unroll
      for (int f = 0; f < 4; ++f) {
        const int ar = wm * 64 + f * 16 + (lane & 15);
        af[f] = *(const bf8*)&ldsA[ar * 64 + ((kq ^ (ar & 7)) * 8)];
        const int br = wn * 64 + f * 16 + (lane & 15);
        bfr[f] = *(const bf8*)&ldsB[br * 64 + ((kq ^ (br & 7)) * 8)];
      }
#pragma unroll
      for (int fm = 0; fm < 4; ++fm)
#pragma unroll
        for (int fn = 0; fn < 4; ++fn)
          acc[fm][fn] = __builtin_amdgcn_mfma_f32_16x16x32_bf16(af[fm], bfr[fn], acc[fm][fn], 0, 0, 0);
    }
    __syncthreads();
  }
  if constexpr (EPI == 1) {
    u16* S2b = (u16*)C + bb * sC;
    float dp[4][4];
#pragma unroll
    for (int fm = 0; fm < 4; ++fm)
#pragma unroll
      for (int r = 0; r < 4; ++r) dp[fm][r] = 0.f;
#pragma unroll
    for (int fm = 0; fm < 4; ++fm) {
      const int m0 = bm + wm * 64 + fm * 16 + ((lane >> 4) << 2);
#pragma unroll
      for (int fn = 0; fn < 4; ++fn) {
        const int n0 = bn + wn * 64 + fn * 16 + (lane & 15);
#pragma unroll
        for (int r = 0; r < 4; ++r) {
          const float v = acc[fm][fn][r];
          const int m = m0 + r;
          if (m < 256) {
            const u16 hi = f2b(v);
            S2b[(long)m * 512 + n0] = hi;
            S2b[(long)m * 512 + 256 + n0] = f2b(v - b2f(hi));
          }
          const float* wr = (m < 256) ? (wqf + (long)m * 256) : (wkf + (long)(m - 256) * 256);
          dp[fm][r] += v * wr[n0];
        }
      }
    }
#pragma unroll
    for (int fm = 0; fm < 4; ++fm)
#pragma unroll
      for (int r = 0; r < 4; ++r) {
        float s = dp[fm][r];
        s += __shfl_xor(s, 1); s += __shfl_xor(s, 2);
        s += __shfl_xor(s, 4); s += __shfl_xor(s, 8);
        if ((lane & 15) == 0) {
          const int m = bm + wm * 64 + fm * 16 + ((lane >> 4) << 2) + r;
          dpart[(long)(blockIdx.y * 2 + wn) * 4096 + bb * 512 + m] = s;
        }
      }
    return;
  }
  if constexpr (EPI == 4) {
    float* odp = (float*)C + bb * sC;
    float* osp = (float*)C + 8388608 + bb * sC;
    const float* fdp = wqf + bb * sC;
    const float* fsp = wkf + bb * sC;
#pragma unroll
    for (int fm = 0; fm < 4; ++fm) {
      const int m0 = bm + wm * 64 + fm * 16 + ((lane >> 4) << 2);
#pragma unroll
      for (int r = 0; r < 4; ++r) {
        const int m = m0 + r;
        const float bv = bias[m];
        const float g1 = dpart[bb * 256 + m];
        const float g2 = poolpart[bb * 256 + m];
        const long rowb = (long)m * ldc;
#pragma unroll
        for (int fn = 0; fn < 4; ++fn) {
          const int n0 = bn + wn * 64 + fn * 16 + (lane & 15);
          const float v = acc[fm][fn][r] + bv;
          odp[rowb + n0] = v * g1 + fdp[rowb + n0];
          osp[rowb + n0] = v * g2 + fsp[rowb + n0];
        }
      }
    }
    return;
  }
  OT* Cb = C + bb * sC + ss * sCs;
#pragma unroll
  for (int fm = 0; fm < 4; ++fm) {
    const int m0 = bm + wm * 64 + fm * 16 + ((lane >> 4) << 2);
#pragma unroll
    for (int fn = 0; fn < 4; ++fn) {
      const int n0 = bn + wn * 64 + fn * 16 + (lane & 15);
#pragma unroll
      for (int r = 0; r < 4; ++r) {
        float v = acc[fm][fn][r];
        if (BIAS == 2) v += bias[m0 + r];
        if constexpr (sizeof(OT) == 2) Cb[(long)(m0 + r) * ldc + n0] = (OT)f2b(v);
        else Cb[(long)(m0 + r) * ldc + n0] = v;
      }
    }
  }
}

// ---- depthwise 3x3 SAME, [B,N,C] bf16 layout ----
__global__ __launch_bounds__(256) void dwconv3x3(const u16* __restrict__ x,
                                                 const float* __restrict__ wdw,
                                                 u16* __restrict__ y) {
  __shared__ float w[9][256];
  const int t = threadIdx.x;
  for (int i = t; i < 2304; i += 256) w[i % 9][i / 9] = wdw[i];
  __syncthreads();
  const int nb = blockIdx.x;
  const int b = nb >> 9;
  const int n0 = (nb & 511) << 3;
  const int tn = t >> 5;
  const int tc = (t & 31) << 3;
  const int n = n0 + tn;
  const int hh = n >> 6, ww2 = n & 63;
  const u16* base = x + ((long)b << 20);
  float acc[8] = {0.f, 0.f, 0.f, 0.f, 0.f, 0.f, 0.f, 0.f};
#pragma unroll
  for (int ky = 0; ky < 3; ++ky) {
    const int hy = hh + ky - 1;
    if ((unsigned)hy >= 64u) continue;
#pragma unroll
    for (int kx = 0; kx < 3; ++kx) {
      const int wx = ww2 + kx - 1;
      if ((unsigned)wx >= 64u) continue;
      const s8v v = *(const s8v*)&base[(((hy << 6) + wx) << 8) + tc];
      const int kk = ky * 3 + kx;
      const fx4 wa = *(const fx4*)&w[kk][tc];
      const fx4 wb = *(const fx4*)&w[kk][tc + 4];
#pragma unroll
      for (int j = 0; j < 4; ++j) {
        acc[j] += wa[j] * b2f((u16)v[j]);
        acc[4 + j] += wb[j] * b2f((u16)v[4 + j]);
      }
    }
  }
  s8v o;
#pragma unroll
  for (int j = 0; j < 8; ++j) o[j] = (short)f2b(acc[j]);
  *(s8v*)&y[((long)b << 20) + ((long)n << 8) + tc] = o;
}

// ---- bf16 transpose + column-sum partials: xt [B,4096,256] -> xtT [B,256,4096]
//      cspart[ntile][b*256+c] = sum of xt over that 32-n tile ----
__global__ void btrans2(const u16* __restrict__ x, u16* __restrict__ y,
                        float* __restrict__ cspart) {
  __shared__ u16 t[32][34];
  __shared__ float ps[8][32];
  const int b = blockIdx.z;
  const int n0 = blockIdx.x * 32;
  const int c0 = blockIdx.y * 32;
  const int tx = threadIdx.x, ty = threadIdx.y;
  const u16* sp = x + (long)b * 1048576 + (long)n0 * 256 + c0;
  float cs = 0.f;
#pragma unroll
  for (int j = 0; j < 4; ++j) {
    int i = ty + j * 8;
    const u16 v = sp[(long)i * 256 + tx];
    t[i][tx] = v;
    cs += b2f(v);
  }
  ps[ty][tx] = cs;
  __syncthreads();
  u16* op = y + (long)b * 1048576 + (long)c0 * 4096 + n0;
#pragma unroll
  for (int j = 0; j < 4; ++j) {
    int r = ty + j * 8;
    op[(long)r * 4096 + tx] = t[tx][r];
  }
  if (ty == 0) {
    float s = 0.f;
#pragma unroll
    for (int k = 0; k < 8; ++k) s += ps[k][tx];
    cspart[(long)blockIdx.x * 2048 + b * 256 + c0 + tx] = s;
  }
}

// ---- sum Gram split-K partials (8) -> hi/lo bf16 G2 [B,256,512] ----
__global__ __launch_bounds__(256) void gsplit(const float* __restrict__ part,
                                              u16* __restrict__ G2) {
  const int i4 = (blockIdx.x * 256 + threadIdx.x) * 4;    // over 524288
  fx4 s = {0.f, 0.f, 0.f, 0.f};
#pragma unroll
  for (int ss = 0; ss < 8; ++ss) s += *(const fx4*)(part + (long)ss * 524288 + i4);
  const int b = i4 >> 16, rem = i4 & 65535, e = rem >> 8, c0 = rem & 255;
  u16* d = G2 + (long)b * 131072 + (long)e * 512 + c0;
  s4v hi, lo;
#pragma unroll
  for (int j = 0; j < 4; ++j) {
    u16 h = f2b(s[j]);
    hi[j] = (short)h;
    lo[j] = (short)f2b(s[j] - b2f(h));
  }
  *(s4v*)d = hi;
  *(s4v*)(d + 256) = lo;
}

// ---- finalize rinv from diag partials + row softmax over d -> bf16 attn ----
__global__ __launch_bounds__(256) void softmax_g2(const float* __restrict__ araw,
                                                  const float* __restrict__ dpart,
                                                  u16* __restrict__ out) {
  const int wid = threadIdx.x >> 6, lane = threadIdx.x & 63;
  const int t = threadIdx.x;
  const int b = blockIdx.x >> 6;
  __shared__ float rq[256];
  float dq = dpart[b * 512 + t] + dpart[4096 + b * 512 + t] +
             dpart[8192 + b * 512 + t] + dpart[12288 + b * 512 + t];
  rq[t] = 1.f / fmaxf(sqrtf(fmaxf(dq, 0.f)), 1e-12f);
  __syncthreads();
  const long row = (long)blockIdx.x * 4 + wid;   // b*256 + c
  const int c = (int)(row & 255);
  const int ki = b * 512 + 256 + c;
  float dk = dpart[ki] + dpart[4096 + ki] + dpart[8192 + ki] + dpart[12288 + ki];
  const float rk = 1.f / fmaxf(sqrtf(fmaxf(dk, 0.f)), 1e-12f);
  fx4 v = ((const fx4*)(araw + row * 256))[lane];
  v[0] *= rk * rq[lane * 4];     v[1] *= rk * rq[lane * 4 + 1];
  v[2] *= rk * rq[lane * 4 + 2]; v[3] *= rk * rq[lane * 4 + 3];
  float m = fmaxf(fmaxf(v[0], v[1]), fmaxf(v[2], v[3]));
#pragma unroll
  for (int o = 32; o > 0; o >>= 1) m = fmaxf(m, __shfl_xor(m, o));
  float e0 = __expf(v[0] - m), e1 = __expf(v[1] - m);
  float e2 = __expf(v[2] - m), e3 = __expf(v[3] - m);
  float s4 = e0 + e1 + e2 + e3;
#pragma unroll
  for (int o = 32; o > 0; o >>= 1) s4 += __shfl_xor(s4, o);
  const float inv = 1.f / s4;
  u16* op = out + row * 256 + lane * 4;
  op[0] = f2b(e0 * inv); op[1] = f2b(e1 * inv);
  op[2] = f2b(e2 * inv); op[3] = f2b(e3 * inv);
}

// ---- fused wfin = Wc @ (attn @ Wv) per (e-tile, batch) block ----
__global__ __launch_bounds__(256) void mwfuse(const u16* __restrict__ attnb,
                                              const u16* __restrict__ wvtb,
                                              const u16* __restrict__ wcb,
                                              u16* __restrict__ wfin) {
  __shared__ u16 lds[25088];           // union, 50 KB
  const int M1OFF = 0;                 // m1T [64][264]
  const int A2OFF = 16896;             // Wc tile [256][32]
  const int B1OFF = 0;                 // phase1 attn [256][64]
  const int A1OFF = 16384;             // phase1 WvT [64][64]
  const int e0 = blockIdx.x * 64;
  const int b = blockIdx.y;
  const int t = threadIdx.x;
  const int wid = t >> 6, lane = t & 63;
  const int srow = t >> 3, slot = t & 7;
  const u16* attn = attnb + (long)b * 65536;

  fx4 acc[4][4] = {};
  for (int kt = 0; kt < 256; kt += 64) {
#pragma unroll
    for (int i = 0; i < 8; ++i) {
      const int row = i * 32 + srow;
      const int kq = slot ^ (row & 7);
      GLOAD(attn + (long)row * 256 + kt + kq * 8, &lds[B1OFF + i * 2048 + wid * 512]);
    }
#pragma unroll
    for (int i = 0; i < 2; ++i) {
      const int row = i * 32 + srow;
      const int kq = slot ^ (row & 7);
      GLOAD(wvtb + (long)(e0 + row) * 256 + kt + kq * 8, &lds[A1OFF + i * 2048 + wid * 512]);
    }
    __syncthreads();
#pragma unroll
    for (int ko = 0; ko < 2; ++ko) {
      bf8 af[4], bfr[4];
      const int kq = ko * 4 + (lane >> 4);
#pragma unroll
      for (int f = 0; f < 4; ++f) {
        const int ar = f * 16 + (lane & 15);
        af[f] = *(const bf8*)&lds[A1OFF + ar * 64 + ((kq ^ (ar & 7)) * 8)];
        const int br = wid * 64 + f * 16 + (lane & 15);
        bfr[f] = *(const bf8*)&lds[B1OFF + br * 64 + ((kq ^ (br & 7)) * 8)];
      }
#pragma unroll
      for (int fm = 0; fm < 4; ++fm)
#pragma unroll
        for (int fn = 0; fn < 4; ++fn)
          acc[fm][fn] = __builtin_amdgcn_mfma_f32_16x16x32_bf16(af[fm], bfr[fn], acc[fm][fn], 0, 0, 0);
    }
    __syncthreads();
  }
#pragma unroll
  for (int fm = 0; fm < 4; ++fm) {
    const int ep0 = fm * 16 + ((lane >> 4) << 2);
#pragma unroll
    for (int fn = 0; fn < 4; ++fn) {
      const int c = wid * 64 + fn * 16 + (lane & 15);
#pragma unroll
      for (int r = 0; r < 4; ++r)
        lds[M1OFF + (ep0 + r) * 264 + c] = f2b(acc[fm][fn][r]);
    }
  }
  __syncthreads();
  fx4 acc2[4][4] = {};
  for (int kt = 0; kt < 256; kt += 32) {
#pragma unroll
    for (int i = 0; i < 4; ++i) {
      const int row = i * 64 + (t >> 2);
      const int kq = (t & 3) ^ (row & 3);
      GLOAD(wcb + (long)row * 256 + kt + kq * 8, &lds[A2OFF + i * 2048 + wid * 512]);
    }
    __syncthreads();
    bf8 af[4], bfr[4];
    const int kq = lane >> 4;
#pragma unroll
    for (int f = 0; f < 4; ++f) {
      const int ar = wid * 64 + f * 16 + (lane & 15);
      af[f] = *(const bf8*)&lds[A2OFF + ar * 32 + ((kq ^ (ar & 3)) * 8)];
      const int br = f * 16 + (lane & 15);
      bfr[f] = *(const bf8*)&lds[M1OFF + br * 264 + kt + kq * 8];
    }
#pragma unroll
    for (int fm = 0; fm < 4; ++fm)
#pragma unroll
      for (int fn = 0; fn < 4; ++fn)
        acc2[fm][fn] = __builtin_amdgcn_mfma_f32_16x16x32_bf16(af[fm], bfr[fn], acc2[fm][fn], 0, 0, 0);
    __syncthreads();
  }
  u16* wf = wfin + (long)b * 65536;
#pragma unroll
  for (int fm = 0; fm < 4; ++fm) {
    const int o0 = wid * 64 + fm * 16 + ((lane >> 4) << 2);
#pragma unroll
    for (int fn = 0; fn < 4; ++fn) {
      const int e = e0 + fn * 16 + (lane & 15);
#pragma unroll
      for (int r = 0; r < 4; ++r)
        wf[(long)(o0 + r) * 256 + e] = f2b(acc2[fm][fn][r]);
    }
  }
}

// ---- SE gates from column-sum partials + wfin matvec + 2-layer MLP ----
__global__ __launch_bounds__(256) void sefuse(const float* __restrict__ cspart,
                                              const u16* __restrict__ wfin,
                                              const float* __restrict__ bcb,
                                              const float* __restrict__ w1d, const float* __restrict__ w2d,
                                              const float* __restrict__ w1s, const float* __restrict__ w2s,
                                              float* __restrict__ gd, float* __restrict__ gs) {
  const int b = blockIdx.x;
  const int t = threadIdx.x;
  __shared__ float xm[256], p[256], hd[16], hs[16];
  float s = 0.f;
#pragma unroll 8
  for (int sl = 0; sl < 128; ++sl) s += cspart[(long)sl * 2048 + b * 256 + t];
  xm[t] = s;
  __syncthreads();
  const u16* wf = wfin + (long)b * 65536 + (long)t * 256;
  float acc = 0.f;
#pragma unroll 4
  for (int e = 0; e < 256; e += 8) {
    const s8v w8 = *(const s8v*)&wf[e];
    const fx4 x0v = *(const fx4*)&xm[e];
    const fx4 x1v = *(const fx4*)&xm[e + 4];
#pragma unroll
    for (int j = 0; j < 4; ++j) {
      acc += b2f((u16)w8[j]) * x0v[j];
      acc += b2f((u16)w8[4 + j]) * x1v[j];
    }
  }
  p[t] = acc * (1.f / 4096.f) + bcb[t];
  __syncthreads();
  if (t < 16) {
    float ad = 0.f, as2 = 0.f;
    for (int j = 0; j < 256; ++j) {
      ad += w1d[t * 256 + j] * p[j];
      as2 += w1s[t * 256 + j] * p[j];
    }
    hd[t] = fmaxf(ad, 0.f);
    hs[t] = fmaxf(as2, 0.f);
  }
  __syncthreads();
  float ad = 0.f, as2 = 0.f;
#pragma unroll
  for (int r = 0; r < 16; ++r) {
    ad += w2d[t * 16 + r] * hd[r];
    as2 += w2s[t * 16 + r] * hs[r];
  }
  gd[b * 256 + t] = 1.f / (1.f + __expf(-ad));
  gs[b * 256 + t] = 1.f / (1.f + __expf(-as2));
}

extern "C" void kernel_launch(void* const* d_in, const int* in_sizes, int n_in,
                              void* d_out, int out_size, void* d_ws, size_t ws_size,
                              hipStream_t stream) {
  const float* fd  = (const float*)d_in[0];
  const float* fs  = (const float*)d_in[1];
  const float* W0  = (const float*)d_in[2];
  const float* Wdw = (const float*)d_in[3];
  const float* Wq  = (const float*)d_in[4];
  const float* Wk  = (const float*)d_in[5];
  const float* Wv  = (const float*)d_in[6];
  const float* Wp  = (const float*)d_in[7];
  const float* bp  = (const float*)d_in[8];
  const float* Wsp = (const float*)d_in[9];
  const float* w1d = (const float*)d_in[10];
  const float* w2d = (const float*)d_in[11];
  const float* w1s = (const float*)d_in[12];
  const float* w2s = (const float*)d_in[13];

  char* ws = (char*)d_ws;
  u16* x0b    = (u16*)(ws + 0);            // [B,N,256] 16.7MB; dead after dwconv
  u16* xtb    = (u16*)(ws + 16777216);     // [B,N,256] 16.7MB; live to final gemm
  u16* xtT    = (u16*)(ws + 33554432);     // [B,256,N] 16.7MB; dead after gram
  float* part = (float*)(ws + 50331648);   // [8][B,256,256] fp32 16.7MB
  u16* G2     = (u16*)(ws + 67108864);     // [B,256,512] hi|lo 2.1MB
  u16* S2     = (u16*)(ws + 69206016);     // [B,256,512] hi|lo 2.1MB
  float* araw = (float*)(ws + 71303168);   // [B,256,256] fp32 2.1MB
  u16* attnb  = (u16*)(ws + 73400320);     // [B,256,256] 1MB
  u16* wfin   = (u16*)(ws + 74448896);     // [B,256,256] 1MB
  u16* w0b    = (u16*)(ws + 75497472);     // [256,512] 256KB
  u16* wqk2   = (u16*)(ws + 75759616);     // [512,512] 512KB
  u16* wvtb   = (u16*)(ws + 76283904);     // [256,256] 128KB
  u16* wcb    = (u16*)(ws + 76414976);     // [256,256] 128KB
  float* bcb  = (float*)(ws + 76546048);   // 256
  float* dpart = (float*)(ws + 76547072);  // [4][B*512] fp32 64KB
  float* cspart = (float*)(ws + 76611584); // [128][B*256] fp32 1MB
  float* gdp  = (float*)(ws + 77660160);   // [B,256]
  float* gsp  = (float*)(ws + 77668352);   // [B,256]
  float* od   = (float*)d_out;

  prep<<<dim3(2048, 4), 256, 0, stream>>>(W0, Wq, Wk, Wv, Wsp, Wp, bp,
                                          w0b, wqk2, wvtb, wcb, bcb);
  conv0f<<<dim3(32, 8), 512, 0, stream>>>(fd, fs, w0b, x0b);
  dwconv3x3<<<4096, 256, 0, stream>>>(x0b, Wdw, xtb);
  btrans2<<<dim3(128, 8, 8), dim3(32, 8), 0, stream>>>(xtb, xtT, cspart);
  // Gram: G[b,c,e] = sum_n xtT[b,c,n] xtT[b,e,n]   M=N=256 K=4096, split-K x8
  gemm_nt<float, 0, 0><<<dim3(2, 2, 64), 256, 0, stream>>>(
      xtT, 1048576, 4096, xtT, 1048576, 4096,
      part, 65536, 524288, 256, nullptr, 512, 8, nullptr, nullptr, nullptr, nullptr);
  gsplit<<<512, 256, 0, stream>>>(part, G2);
  // SS = Wqk @ G  (M=512 N=256 K=512 hi|lo) with fused S2-split + diag partials
  gemm_nt<u16, 0, 1><<<dim3(4, 2, 8), 256, 0, stream>>>(
      wqk2, 0, 512, G2, 131072, 512, S2, 131072, 0, 512, nullptr, 512, 1,
      Wq, Wk, dpart, nullptr);
  // araw = Wk G Wq^T: A=[Wk|Wk], B=S2 hi|lo   M=N=256 K=512
  gemm_nt<float, 0, 0><<<dim3(2, 2, 8), 256, 0, stream>>>(
      wqk2 + 131072, 0, 512, S2, 131072, 512, araw, 65536, 0, 256, nullptr, 512, 1,
      nullptr, nullptr, nullptr, nullptr);
  softmax_g2<<<512, 256, 0, stream>>>(araw, dpart, attnb);
  // wfin = Wc @ attn @ Wv (fused two-stage)
  mwfuse<<<dim3(4, 8), 256, 0, stream>>>(attnb, wvtb, wcb, wfin);
  // SE gates from linearity: pool = Wfin @ colsum(xt)/4096 + bc
  sefuse<<<8, 256, 0, stream>>>(cspart, wfin, bcb, w1d, w2d, w1s, w2s, gdp, gsp);
  // final: od/os[b,o,n] = (sum_e wfin[b,o,e] xt[b,n,e] + bc[o])*g + residual
  gemm_nt<float, 0, 4><<<dim3(2, 32, 8), 256, 0, stream>>>(
      wfin, 65536, 256, xtb, 1048576, 256, od, 1048576, 0, 4096, bcb, 256, 1,
      fd, fs, gdp, gsp);
}

// Round 11
// 165.809 us; speedup vs baseline: 1.3858x; 1.0172x over previous
//
#include <hip/hip_runtime.h>
#include <cstdint>

#define DEVI __device__ __forceinline__

using fx4 = __attribute__((ext_vector_type(4))) float;
using bf8 = __attribute__((ext_vector_type(8))) __bf16;
using s8v = __attribute__((ext_vector_type(8))) short;
using s4v = __attribute__((ext_vector_type(4))) short;
typedef unsigned short u16;
typedef unsigned int u32;

DEVI float b2f(u16 u) { return __builtin_bit_cast(float, (u32)u << 16); }
DEVI u16 f2b(float f) {
  u32 u = __builtin_bit_cast(u32, f);
  return (u16)((u + 0x7fffu + ((u >> 16) & 1u)) >> 16);
}

// async global->LDS, 16B per lane, dest = wave-uniform base + lane*16
#define GLOAD(g, l)                                                          \
  __builtin_amdgcn_global_load_lds(                                          \
      (const __attribute__((address_space(1))) unsigned int*)(g),            \
      (__attribute__((address_space(3))) unsigned int*)(l), 16, 0, 0)

// ---- weight prep: W0->bf16; wqk2=[Wq|Wq ; Wk|Wk]; WvT; Wc=Wsp@Wp, bc=Wsp@bp ----
__global__ __launch_bounds__(256) void prep(const float* __restrict__ W0,
                                            const float* __restrict__ Wq,
                                            const float* __restrict__ Wk,
                                            const float* __restrict__ Wv,
                                            const float* __restrict__ Wsp,
                                            const float* __restrict__ Wp,
                                            const float* __restrict__ bp,
                                            u16* __restrict__ w0b,
                                            u16* __restrict__ wqk2,
                                            u16* __restrict__ wvtb,
                                            u16* __restrict__ wcb,
                                            float* __restrict__ bcb) {
  __shared__ float row[256];
  __shared__ float red[4];
  const int y = blockIdx.y;
  const int t = threadIdx.x;
  if (y == 0) {
    const int i = blockIdx.x * 256 + t;
    if (i < 131072) w0b[i] = f2b(W0[i]);
  } else if (y == 1) {
    const int i = blockIdx.x * 256 + t;
    // wqk2 is [512][512] = 262144 elements (R7/R8 bug was a 2x overrun here).
    if (i < 262144) {
      const int r = i >> 9, c = i & 511;
      const float* src = (r < 256) ? Wq : Wk;
      wqk2[i] = f2b(src[((r & 255) << 8) + (c & 255)]);
    }
  } else if (y == 2) {
    const int i = blockIdx.x * 256 + t;
    if (i < 65536) {
      const int e = i >> 8, d = i & 255;
      wvtb[i] = f2b(Wv[d * 256 + e]);          // WvT[e,d] = Wv[d,e]
    }
  } else {
    if (blockIdx.x >= 256) return;
    const int o = blockIdx.x;
    row[t] = Wsp[o * 256 + t];
    __syncthreads();
    float acc = 0.f;
    for (int c = 0; c < 256; ++c) acc += row[c] * Wp[c * 256 + t];
    wcb[o * 256 + t] = f2b(acc);
    float pb = row[t] * bp[t];
#pragma unroll
    for (int m = 32; m > 0; m >>= 1) pb += __shfl_xor(pb, m);
    if ((t & 63) == 0) red[t >> 6] = pb;
    __syncthreads();
    if (t == 0) bcb[o] = red[0] + red[1] + red[2] + red[3];
  }
}

// ---- fused concat+1x1 conv: x0[b,n,o] = sum_c [fd;fs][b,c,n] * W0[o,c] ----
__global__ __launch_bounds__(512) void conv0f(const float* __restrict__ fd,
                                              const float* __restrict__ fs,
                                              const u16* __restrict__ w0b,
                                              u16* __restrict__ x0) {
  __shared__ u16 tmp[64 * 132];     // [c][n], pad 4
  __shared__ u16 ldsA[128 * 64];    // [n][c] chunk-swizzled
  __shared__ u16 ldsB[256 * 64];    // [o][c] linear (GLOAD)
  const int b = blockIdx.y;
  const int bm = blockIdx.x * 128;
  const int t = threadIdx.x;
  const int wid = t >> 6, lane = t & 63;
  const int wm = wid >> 2, wn = wid & 3;
  fx4 acc[4][4] = {};
  for (int kt = 0; kt < 512; kt += 64) {
#pragma unroll
    for (int i = 0; i < 4; ++i) {
      const int r = i * 64 + (t >> 3);
      const int kq = (t & 7) ^ (r & 7);
      GLOAD(w0b + (long)r * 512 + kt + kq * 8, &ldsB[i * 4096 + wid * 512]);
    }
    const float* src = ((kt < 256) ? fd : fs) + ((long)b * 256 + (kt & 255)) * 4096L + bm;
#pragma unroll
    for (int p = 0; p < 4; ++p) {
      const int c = (t >> 5) + p * 16;
      const int n4 = (t & 31) * 4;
      const fx4 v = *(const fx4*)&src[(long)c * 4096 + n4];
      s4v pk;
#pragma unroll
      for (int j = 0; j < 4; ++j) pk[j] = (short)f2b(v[j]);
      *(s4v*)&tmp[c * 132 + n4] = pk;
    }
    __syncthreads();
#pragma unroll
    for (int pass = 0; pass < 2; ++pass) {
      const int n = t & 127;
      const int g = (t >> 7) + pass * 4;
      s8v pk;
#pragma unroll
      for (int j = 0; j < 8; ++j) pk[j] = (short)tmp[(g * 8 + j) * 132 + n];
      *(s8v*)&ldsA[n * 64 + ((g ^ (n & 7)) * 8)] = pk;
    }
    __syncthreads();
#pragma unroll
    for (int ko = 0; ko < 2; ++ko) {
      bf8 af[4], bfr[4];
      const int kq = ko * 4 + (lane >> 4);
#pragma unroll
      for (int f = 0; f < 4; ++f) {
        const int ar = wm * 64 + f * 16 + (lane & 15);
        af[f] = *(const bf8*)&ldsA[ar * 64 + ((kq ^ (ar & 7)) * 8)];
        const int br = wn * 64 + f * 16 + (lane & 15);
        bfr[f] = *(const bf8*)&ldsB[br * 64 + ((kq ^ (br & 7)) * 8)];
      }
#pragma unroll
      for (int fm = 0; fm < 4; ++fm)
#pragma unroll
        for (int fn = 0; fn < 4; ++fn)
          acc[fm][fn] = __builtin_amdgcn_mfma_f32_16x16x32_bf16(af[fm], bfr[fn], acc[fm][fn], 0, 0, 0);
    }
    __syncthreads();
  }
#pragma unroll
  for (int fm = 0; fm < 4; ++fm) {
    const int m0 = wm * 64 + fm * 16 + ((lane >> 4) << 2);
#pragma unroll
    for (int fn = 0; fn < 4; ++fn) {
      const int o = wn * 64 + fn * 16 + (lane & 15);
#pragma unroll
      for (int r = 0; r < 4; ++r)
        x0[((long)b << 20) + (long)(bm + m0 + r) * 256 + o] = f2b(acc[fm][fn][r]);
    }
  }
}

// ---- bf16 NT GEMM: C[m,n] = sum_k A[m,k]*B[n,k] ----
// EPI: 0 normal; 1 = S2 hi/lo (rows<256) + diag partials;
//      4 = dual-gated residual write: od/os = (acc+bias[m])*g + residual.
//      (EPI=4 arg mapping: wqf=fd, wkf=fs, dpart=gd, poolpart=gs, bias=bc)
template <typename OT, int BIAS, int EPI>
__global__ __launch_bounds__(256) void gemm_nt(
    const u16* __restrict__ A, long sA, int lda,
    const u16* __restrict__ B, long sB, int ldb,
    OT* __restrict__ C, long sC, long sCs, int ldc,
    const float* __restrict__ bias, int Keff, int ksplit,
    const float* __restrict__ wqf, const float* __restrict__ wkf,
    float* __restrict__ dpart, float* __restrict__ poolpart) {
  __shared__ u16 ldsA[128 * 64];
  __shared__ u16 ldsB[128 * 64];
  const int z = blockIdx.z;
  const int bb = z / ksplit;
  const int ss = z - bb * ksplit;
  const int bm = blockIdx.x * 128;
  const int bn = blockIdx.y * 128;
  const u16* Ab = A + bb * sA + (long)ss * Keff + (long)bm * lda;
  const u16* Bb = B + bb * sB + (long)ss * Keff + (long)bn * ldb;
  const int tid = threadIdx.x;
  const int wid = tid >> 6;
  const int lane = tid & 63;
  const int wm = wid >> 1, wn = wid & 1;
  const int srow = tid >> 3;
  const int slot = tid & 7;

  fx4 acc[4][4] = {};
  for (int kt = 0; kt < Keff; kt += 64) {
#pragma unroll
    for (int i = 0; i < 4; ++i) {
      const int row = i * 32 + srow;
      const int kq = slot ^ (row & 7);
      GLOAD(Ab + (long)row * lda + kt + kq * 8, &ldsA[i * 2048 + wid * 512]);
      GLOAD(Bb + (long)row * ldb + kt + kq * 8, &ldsB[i * 2048 + wid * 512]);
    }
    __syncthreads();
#pragma unroll
    for (int ko = 0; ko < 2; ++ko) {
      bf8 af[4], bfr[4];
      const int kq = ko * 4 + (lane >> 4);
#pragma unroll
      for (int f = 0; f < 4; ++f) {
        const int ar = wm * 64 + f * 16 + (lane & 15);
        af[f] = *(const bf8*)&ldsA[ar * 64 + ((kq ^ (ar & 7)) * 8)];
        const int br = wn * 64 + f * 16 + (lane & 15);
        bfr[f] = *(const bf8*)&ldsB[br * 64 + ((kq ^ (br & 7)) * 8)];
      }
#pragma unroll
      for (int fm = 0; fm < 4; ++fm)
#pragma unroll
        for (int fn = 0; fn < 4; ++fn)
          acc[fm][fn] = __builtin_amdgcn_mfma_f32_16x16x32_bf16(af[fm], bfr[fn], acc[fm][fn], 0, 0, 0);
    }
    __syncthreads();
  }
  if constexpr (EPI == 1) {
    u16* S2b = (u16*)C + bb * sC;
    float dp[4][4];
#pragma unroll
    for (int fm = 0; fm < 4; ++fm)
#pragma unroll
      for (int r = 0; r < 4; ++r) dp[fm][r] = 0.f;
#pragma unroll
    for (int fm = 0; fm < 4; ++fm) {
      const int m0 = bm + wm * 64 + fm * 16 + ((lane >> 4) << 2);
#pragma unroll
      for (int fn = 0; fn < 4; ++fn) {
        const int n0 = bn + wn * 64 + fn * 16 + (lane & 15);
#pragma unroll
        for (int r = 0; r < 4; ++r) {
          const float v = acc[fm][fn][r];
          const int m = m0 + r;
          if (m < 256) {
            const u16 hi = f2b(v);
            S2b[(long)m * 512 + n0] = hi;
            S2b[(long)m * 512 + 256 + n0] = f2b(v - b2f(hi));
          }
          const float* wr = (m < 256) ? (wqf + (long)m * 256) : (wkf + (long)(m - 256) * 256);
          dp[fm][r] += v * wr[n0];
        }
      }
    }
#pragma unroll
    for (int fm = 0; fm < 4; ++fm)
#pragma unroll
      for (int r = 0; r < 4; ++r) {
        float s = dp[fm][r];
        s += __shfl_xor(s, 1); s += __shfl_xor(s, 2);
        s += __shfl_xor(s, 4); s += __shfl_xor(s, 8);
        if ((lane & 15) == 0) {
          const int m = bm + wm * 64 + fm * 16 + ((lane >> 4) << 2) + r;
          dpart[(long)(blockIdx.y * 2 + wn) * 4096 + bb * 512 + m] = s;
        }
      }
    return;
  }
  if constexpr (EPI == 4) {
    float* odp = (float*)C + bb * sC;
    float* osp = (float*)C + 8388608 + bb * sC;
    const float* fdp = wqf + bb * sC;
    const float* fsp = wkf + bb * sC;
#pragma unroll
    for (int fm = 0; fm < 4; ++fm) {
      const int m0 = bm + wm * 64 + fm * 16 + ((lane >> 4) << 2);
#pragma unroll
      for (int r = 0; r < 4; ++r) {
        const int m = m0 + r;
        const float bv = bias[m];
        const float g1 = dpart[bb * 256 + m];
        const float g2 = poolpart[bb * 256 + m];
        const long rowb = (long)m * ldc;
#pragma unroll
        for (int fn = 0; fn < 4; ++fn) {
          const int n0 = bn + wn * 64 + fn * 16 + (lane & 15);
          const float v = acc[fm][fn][r] + bv;
          odp[rowb + n0] = v * g1 + fdp[rowb + n0];
          osp[rowb + n0] = v * g2 + fsp[rowb + n0];
        }
      }
    }
    return;
  }
  OT* Cb = C + bb * sC + ss * sCs;
#pragma unroll
  for (int fm = 0; fm < 4; ++fm) {
    const int m0 = bm + wm * 64 + fm * 16 + ((lane >> 4) << 2);
#pragma unroll
    for (int fn = 0; fn < 4; ++fn) {
      const int n0 = bn + wn * 64 + fn * 16 + (lane & 15);
#pragma unroll
      for (int r = 0; r < 4; ++r) {
        float v = acc[fm][fn][r];
        if (BIAS == 2) v += bias[m0 + r];
        if constexpr (sizeof(OT) == 2) Cb[(long)(m0 + r) * ldc + n0] = (OT)f2b(v);
        else Cb[(long)(m0 + r) * ldc + n0] = v;
      }
    }
  }
}

// ---- fused depthwise 3x3 + transpose + column-sum partials ----
// block = 32-token strip x 256 ch; writes xt [B,N,C], xtT [B,C,N], cspart.
// Same per-element math as the previous dwconv3x3 (bit-identical xt/xtT).
__global__ __launch_bounds__(256) void dwconvT(const u16* __restrict__ x,
                                               const float* __restrict__ wdw,
                                               u16* __restrict__ y,
                                               u16* __restrict__ yT,
                                               float* __restrict__ cspart) {
  __shared__ float w[9][256];
  __shared__ u16 tb2[32][264];      // [n][c], pad 8 u16 (row 528B: 16B-aligned, bank-spread)
  __shared__ float psf[8][256];     // per-tn column-sum partials
  const int t = threadIdx.x;
  for (int i = t; i < 2304; i += 256) w[i % 9][i / 9] = wdw[i];
  const int b = blockIdx.x >> 7;
  const int strip = blockIdx.x & 127;
  const int n0 = strip * 32;
  const int h = n0 >> 6;
  const int w0 = n0 & 63;
  const int tc = (t & 31) * 8;
  const int tn = t >> 5;            // 0..7
  const u16* base = x + ((long)b << 20);
  float csl[8] = {0.f, 0.f, 0.f, 0.f, 0.f, 0.f, 0.f, 0.f};
  __syncthreads();
#pragma unroll
  for (int p = 0; p < 4; ++p) {
    const int nn = p * 8 + tn;      // 0..31 within strip
    const int ww = w0 + nn;
    float acc[8] = {0.f, 0.f, 0.f, 0.f, 0.f, 0.f, 0.f, 0.f};
#pragma unroll
    for (int ky = 0; ky < 3; ++ky) {
      const int hy = h + ky - 1;
      if ((unsigned)hy >= 64u) continue;
#pragma unroll
      for (int kx = 0; kx < 3; ++kx) {
        const int wx = ww + kx - 1;
        if ((unsigned)wx >= 64u) continue;
        const s8v v = *(const s8v*)&base[(((hy << 6) + wx) << 8) + tc];
        const int kk = ky * 3 + kx;
        const fx4 wa = *(const fx4*)&w[kk][tc];
        const fx4 wb = *(const fx4*)&w[kk][tc + 4];
#pragma unroll
        for (int j = 0; j < 4; ++j) {
          acc[j] += wa[j] * b2f((u16)v[j]);
          acc[4 + j] += wb[j] * b2f((u16)v[4 + j]);
        }
      }
    }
    s8v o;
#pragma unroll
    for (int j = 0; j < 8; ++j) {
      o[j] = (short)f2b(acc[j]);
      csl[j] += b2f((u16)o[j]);     // sum the ROUNDED value (matches btrans2 semantics)
    }
    *(s8v*)&y[((long)b << 20) + (long)((n0 + nn) << 8) + tc] = o;
    *(s8v*)&tb2[nn][tc] = o;
  }
#pragma unroll
  for (int j = 0; j < 8; ++j) psf[tn][tc + j] = csl[j];
  __syncthreads();
  // transposed write: 8 c-rows x 32 n per iteration, 64B contiguous per row
  const int cg = t >> 5;            // row-group within iter
  const int nn2 = t & 31;
  u16* yb = yT + ((long)b << 20);
#pragma unroll
  for (int cb = 0; cb < 256; cb += 8) {
    const int c = cb + cg;
    yb[(long)c * 4096 + n0 + nn2] = tb2[nn2][c];
  }
  // column sums -> cspart[strip][b*256 + c]
  if (t < 256) {
    float s = 0.f;
#pragma unroll
    for (int k = 0; k < 8; ++k) s += psf[k][t];
    cspart[(long)strip * 2048 + b * 256 + t] = s;
  }
}

// ---- sum Gram split-K partials (8) -> hi/lo bf16 G2 [B,256,512] ----
__global__ __launch_bounds__(256) void gsplit(const float* __restrict__ part,
                                              u16* __restrict__ G2) {
  const int i4 = (blockIdx.x * 256 + threadIdx.x) * 4;    // over 524288
  fx4 s = {0.f, 0.f, 0.f, 0.f};
#pragma unroll
  for (int ss = 0; ss < 8; ++ss) s += *(const fx4*)(part + (long)ss * 524288 + i4);
  const int b = i4 >> 16, rem = i4 & 65535, e = rem >> 8, c0 = rem & 255;
  u16* d = G2 + (long)b * 131072 + (long)e * 512 + c0;
  s4v hi, lo;
#pragma unroll
  for (int j = 0; j < 4; ++j) {
    u16 h = f2b(s[j]);
    hi[j] = (short)h;
    lo[j] = (short)f2b(s[j] - b2f(h));
  }
  *(s4v*)d = hi;
  *(s4v*)(d + 256) = lo;
}

// ---- finalize rinv from diag partials + row softmax over d -> bf16 attn ----
__global__ __launch_bounds__(256) void softmax_g2(const float* __restrict__ araw,
                                                  const float* __restrict__ dpart,
                                                  u16* __restrict__ out) {
  const int wid = threadIdx.x >> 6, lane = threadIdx.x & 63;
  const int t = threadIdx.x;
  const int b = blockIdx.x >> 6;
  __shared__ float rq[256];
  float dq = dpart[b * 512 + t] + dpart[4096 + b * 512 + t] +
             dpart[8192 + b * 512 + t] + dpart[12288 + b * 512 + t];
  rq[t] = 1.f / fmaxf(sqrtf(fmaxf(dq, 0.f)), 1e-12f);
  __syncthreads();
  const long row = (long)blockIdx.x * 4 + wid;   // b*256 + c
  const int c = (int)(row & 255);
  const int ki = b * 512 + 256 + c;
  float dk = dpart[ki] + dpart[4096 + ki] + dpart[8192 + ki] + dpart[12288 + ki];
  const float rk = 1.f / fmaxf(sqrtf(fmaxf(dk, 0.f)), 1e-12f);
  fx4 v = ((const fx4*)(araw + row * 256))[lane];
  v[0] *= rk * rq[lane * 4];     v[1] *= rk * rq[lane * 4 + 1];
  v[2] *= rk * rq[lane * 4 + 2]; v[3] *= rk * rq[lane * 4 + 3];
  float m = fmaxf(fmaxf(v[0], v[1]), fmaxf(v[2], v[3]));
#pragma unroll
  for (int o = 32; o > 0; o >>= 1) m = fmaxf(m, __shfl_xor(m, o));
  float e0 = __expf(v[0] - m), e1 = __expf(v[1] - m);
  float e2 = __expf(v[2] - m), e3 = __expf(v[3] - m);
  float s4 = e0 + e1 + e2 + e3;
#pragma unroll
  for (int o = 32; o > 0; o >>= 1) s4 += __shfl_xor(s4, o);
  const float inv = 1.f / s4;
  u16* op = out + row * 256 + lane * 4;
  op[0] = f2b(e0 * inv); op[1] = f2b(e1 * inv);
  op[2] = f2b(e2 * inv); op[3] = f2b(e3 * inv);
}

// ---- fused wfin = Wc @ (attn @ Wv) per (e-tile, batch) block ----
__global__ __launch_bounds__(256) void mwfuse(const u16* __restrict__ attnb,
                                              const u16* __restrict__ wvtb,
                                              const u16* __restrict__ wcb,
                                              u16* __restrict__ wfin) {
  __shared__ u16 lds[25088];           // union, 50 KB
  const int M1OFF = 0;                 // m1T [64][264]
  const int A2OFF = 16896;             // Wc tile [256][32]
  const int B1OFF = 0;                 // phase1 attn [256][64]
  const int A1OFF = 16384;             // phase1 WvT [64][64]
  const int e0 = blockIdx.x * 64;
  const int b = blockIdx.y;
  const int t = threadIdx.x;
  const int wid = t >> 6, lane = t & 63;
  const int srow = t >> 3, slot = t & 7;
  const u16* attn = attnb + (long)b * 65536;

  fx4 acc[4][4] = {};
  for (int kt = 0; kt < 256; kt += 64) {
#pragma unroll
    for (int i = 0; i < 8; ++i) {
      const int row = i * 32 + srow;
      const int kq = slot ^ (row & 7);
      GLOAD(attn + (long)row * 256 + kt + kq * 8, &lds[B1OFF + i * 2048 + wid * 512]);
    }
#pragma unroll
    for (int i = 0; i < 2; ++i) {
      const int row = i * 32 + srow;
      const int kq = slot ^ (row & 7);
      GLOAD(wvtb + (long)(e0 + row) * 256 + kt + kq * 8, &lds[A1OFF + i * 2048 + wid * 512]);
    }
    __syncthreads();
#pragma unroll
    for (int ko = 0; ko < 2; ++ko) {
      bf8 af[4], bfr[4];
      const int kq = ko * 4 + (lane >> 4);
#pragma unroll
      for (int f = 0; f < 4; ++f) {
        const int ar = f * 16 + (lane & 15);
        af[f] = *(const bf8*)&lds[A1OFF + ar * 64 + ((kq ^ (ar & 7)) * 8)];
        const int br = wid * 64 + f * 16 + (lane & 15);
        bfr[f] = *(const bf8*)&lds[B1OFF + br * 64 + ((kq ^ (br & 7)) * 8)];
      }
#pragma unroll
      for (int fm = 0; fm < 4; ++fm)
#pragma unroll
        for (int fn = 0; fn < 4; ++fn)
          acc[fm][fn] = __builtin_amdgcn_mfma_f32_16x16x32_bf16(af[fm], bfr[fn], acc[fm][fn], 0, 0, 0);
    }
    __syncthreads();
  }
#pragma unroll
  for (int fm = 0; fm < 4; ++fm) {
    const int ep0 = fm * 16 + ((lane >> 4) << 2);
#pragma unroll
    for (int fn = 0; fn < 4; ++fn) {
      const int c = wid * 64 + fn * 16 + (lane & 15);
#pragma unroll
      for (int r = 0; r < 4; ++r)
        lds[M1OFF + (ep0 + r) * 264 + c] = f2b(acc[fm][fn][r]);
    }
  }
  __syncthreads();
  fx4 acc2[4][4] = {};
  for (int kt = 0; kt < 256; kt += 32) {
#pragma unroll
    for (int i = 0; i < 4; ++i) {
      const int row = i * 64 + (t >> 2);
      const int kq = (t & 3) ^ (row & 3);
      GLOAD(wcb + (long)row * 256 + kt + kq * 8, &lds[A2OFF + i * 2048 + wid * 512]);
    }
    __syncthreads();
    bf8 af[4], bfr[4];
    const int kq = lane >> 4;
#pragma unroll
    for (int f = 0; f < 4; ++f) {
      const int ar = wid * 64 + f * 16 + (lane & 15);
      af[f] = *(const bf8*)&lds[A2OFF + ar * 32 + ((kq ^ (ar & 3)) * 8)];
      const int br = f * 16 + (lane & 15);
      bfr[f] = *(const bf8*)&lds[M1OFF + br * 264 + kt + kq * 8];
    }
#pragma unroll
    for (int fm = 0; fm < 4; ++fm)
#pragma unroll
      for (int fn = 0; fn < 4; ++fn)
        acc2[fm][fn] = __builtin_amdgcn_mfma_f32_16x16x32_bf16(af[fm], bfr[fn], acc2[fm][fn], 0, 0, 0);
    __syncthreads();
  }
  u16* wf = wfin + (long)b * 65536;
#pragma unroll
  for (int fm = 0; fm < 4; ++fm) {
    const int o0 = wid * 64 + fm * 16 + ((lane >> 4) << 2);
#pragma unroll
    for (int fn = 0; fn < 4; ++fn) {
      const int e = e0 + fn * 16 + (lane & 15);
#pragma unroll
      for (int r = 0; r < 4; ++r)
        wf[(long)(o0 + r) * 256 + e] = f2b(acc2[fm][fn][r]);
    }
  }
}

// ---- SE gates from column-sum partials + wfin matvec + 2-layer MLP ----
__global__ __launch_bounds__(256) void sefuse(const float* __restrict__ cspart,
                                              const u16* __restrict__ wfin,
                                              const float* __restrict__ bcb,
                                              const float* __restrict__ w1d, const float* __restrict__ w2d,
                                              const float* __restrict__ w1s, const float* __restrict__ w2s,
                                              float* __restrict__ gd, float* __restrict__ gs) {
  const int b = blockIdx.x;
  const int t = threadIdx.x;
  __shared__ float xm[256], p[256], hd[16], hs[16];
  float s = 0.f;
#pragma unroll 8
  for (int sl = 0; sl < 128; ++sl) s += cspart[(long)sl * 2048 + b * 256 + t];
  xm[t] = s;
  __syncthreads();
  const u16* wf = wfin + (long)b * 65536 + (long)t * 256;
  float acc = 0.f;
#pragma unroll 4
  for (int e = 0; e < 256; e += 8) {
    const s8v w8 = *(const s8v*)&wf[e];
    const fx4 x0v = *(const fx4*)&xm[e];
    const fx4 x1v = *(const fx4*)&xm[e + 4];
#pragma unroll
    for (int j = 0; j < 4; ++j) {
      acc += b2f((u16)w8[j]) * x0v[j];
      acc += b2f((u16)w8[4 + j]) * x1v[j];
    }
  }
  p[t] = acc * (1.f / 4096.f) + bcb[t];
  __syncthreads();
  if (t < 16) {
    float ad = 0.f, as2 = 0.f;
    for (int j = 0; j < 256; ++j) {
      ad += w1d[t * 256 + j] * p[j];
      as2 += w1s[t * 256 + j] * p[j];
    }
    hd[t] = fmaxf(ad, 0.f);
    hs[t] = fmaxf(as2, 0.f);
  }
  __syncthreads();
  float ad = 0.f, as2 = 0.f;
#pragma unroll
  for (int r = 0; r < 16; ++r) {
    ad += w2d[t * 16 + r] * hd[r];
    as2 += w2s[t * 16 + r] * hs[r];
  }
  gd[b * 256 + t] = 1.f / (1.f + __expf(-ad));
  gs[b * 256 + t] = 1.f / (1.f + __expf(-as2));
}

extern "C" void kernel_launch(void* const* d_in, const int* in_sizes, int n_in,
                              void* d_out, int out_size, void* d_ws, size_t ws_size,
                              hipStream_t stream) {
  const float* fd  = (const float*)d_in[0];
  const float* fs  = (const float*)d_in[1];
  const float* W0  = (const float*)d_in[2];
  const float* Wdw = (const float*)d_in[3];
  const float* Wq  = (const float*)d_in[4];
  const float* Wk  = (const float*)d_in[5];
  const float* Wv  = (const float*)d_in[6];
  const float* Wp  = (const float*)d_in[7];
  const float* bp  = (const float*)d_in[8];
  const float* Wsp = (const float*)d_in[9];
  const float* w1d = (const float*)d_in[10];
  const float* w2d = (const float*)d_in[11];
  const float* w1s = (const float*)d_in[12];
  const float* w2s = (const float*)d_in[13];

  char* ws = (char*)d_ws;
  u16* x0b    = (u16*)(ws + 0);            // [B,N,256] 16.7MB; dead after dwconvT
  u16* xtb    = (u16*)(ws + 16777216);     // [B,N,256] 16.7MB; live to final gemm
  u16* xtT    = (u16*)(ws + 33554432);     // [B,256,N] 16.7MB; dead after gram
  float* part = (float*)(ws + 50331648);   // [8][B,256,256] fp32 16.7MB
  u16* G2     = (u16*)(ws + 67108864);     // [B,256,512] hi|lo 2.1MB
  u16* S2     = (u16*)(ws + 69206016);     // [B,256,512] hi|lo 2.1MB
  float* araw = (float*)(ws + 71303168);   // [B,256,256] fp32 2.1MB
  u16* attnb  = (u16*)(ws + 73400320);     // [B,256,256] 1MB
  u16* wfin   = (u16*)(ws + 74448896);     // [B,256,256] 1MB
  u16* w0b    = (u16*)(ws + 75497472);     // [256,512] 256KB
  u16* wqk2   = (u16*)(ws + 75759616);     // [512,512] 512KB
  u16* wvtb   = (u16*)(ws + 76283904);     // [256,256] 128KB
  u16* wcb    = (u16*)(ws + 76414976);     // [256,256] 128KB
  float* bcb  = (float*)(ws + 76546048);   // 256
  float* dpart = (float*)(ws + 76547072);  // [4][B*512] fp32 64KB
  float* cspart = (float*)(ws + 76611584); // [128][B*256] fp32 1MB
  float* gdp  = (float*)(ws + 77660160);   // [B,256]
  float* gsp  = (float*)(ws + 77668352);   // [B,256]
  float* od   = (float*)d_out;

  prep<<<dim3(2048, 4), 256, 0, stream>>>(W0, Wq, Wk, Wv, Wsp, Wp, bp,
                                          w0b, wqk2, wvtb, wcb, bcb);
  conv0f<<<dim3(32, 8), 512, 0, stream>>>(fd, fs, w0b, x0b);
  // fused depthwise conv + transpose + column sums
  dwconvT<<<1024, 256, 0, stream>>>(x0b, Wdw, xtb, xtT, cspart);
  // Gram: G[b,c,e] = sum_n xtT[b,c,n] xtT[b,e,n]   M=N=256 K=4096, split-K x8
  gemm_nt<float, 0, 0><<<dim3(2, 2, 64), 256, 0, stream>>>(
      xtT, 1048576, 4096, xtT, 1048576, 4096,
      part, 65536, 524288, 256, nullptr, 512, 8, nullptr, nullptr, nullptr, nullptr);
  gsplit<<<512, 256, 0, stream>>>(part, G2);
  // SS = Wqk @ G  (M=512 N=256 K=512 hi|lo) with fused S2-split + diag partials
  gemm_nt<u16, 0, 1><<<dim3(4, 2, 8), 256, 0, stream>>>(
      wqk2, 0, 512, G2, 131072, 512, S2, 131072, 0, 512, nullptr, 512, 1,
      Wq, Wk, dpart, nullptr);
  // araw = Wk G Wq^T: A=[Wk|Wk], B=S2 hi|lo   M=N=256 K=512
  gemm_nt<float, 0, 0><<<dim3(2, 2, 8), 256, 0, stream>>>(
      wqk2 + 131072, 0, 512, S2, 131072, 512, araw, 65536, 0, 256, nullptr, 512, 1,
      nullptr, nullptr, nullptr, nullptr);
  softmax_g2<<<512, 256, 0, stream>>>(araw, dpart, attnb);
  // wfin = Wc @ attn @ Wv (fused two-stage)
  mwfuse<<<dim3(4, 8), 256, 0, stream>>>(attnb, wvtb, wcb, wfin);
  // SE gates from linearity: pool = Wfin @ colsum(xt)/4096 + bc
  sefuse<<<8, 256, 0, stream>>>(cspart, wfin, bcb, w1d, w2d, w1s, w2s, gdp, gsp);
  // final: od/os[b,o,n] = (sum_e wfin[b,o,e] xt[b,n,e] + bc[o])*g + residual
  gemm_nt<float, 0, 4><<<dim3(2, 32, 8), 256, 0, stream>>>(
      wfin, 65536, 256, xtb, 1048576, 256, od, 1048576, 0, 4096, bcb, 256, 1,
      fd, fs, gdp, gsp);
}